// Round 13
// baseline (249.007 us; speedup 1.0000x reference)
//
#include <hip/hip_runtime.h>
#include <cstdint>

#define NN 100000
#define NE 1600000
#define NG 64
#define NH 128
#define NC 10
#define EPSV 1e-5f

#define NB 782                       // (NN+127)>>7 coarse buckets (128 nodes each)
#define NBLK 512                     // histogram/scatter blocks
#define EPB ((NE + NBLK - 1) / NBLK) // 3125 edges per block
#define NSCAN (NB * NBLK)            // 400384, divisible by 1024
#define NSB (NSCAN / 1024)           // 391 scan blocks

typedef __attribute__((ext_vector_type(8))) short bf16x8;
typedef __attribute__((ext_vector_type(4))) float f32x4;
typedef __attribute__((ext_vector_type(2))) float f32x2;
typedef __attribute__((ext_vector_type(4))) uint u32x4;
typedef unsigned long long u64;
typedef unsigned char uchar;

__device__ __forceinline__ ushort f2b(float f) {
  uint u = __builtin_bit_cast(uint, f);
  u = (u + 0x7FFFu + ((u >> 16) & 1u)) >> 16;
  return (ushort)u;
}
__device__ __forceinline__ float b2f(ushort h) {
  return __builtin_bit_cast(float, ((uint)h) << 16);
}

// ---------------- graph prep: counting sort by destination ----------------
// also zeroes row NN of both feature buffers (gather-pad target)
__global__ __launch_bounds__(128) void k_gstart2(const int* __restrict__ batch,
                                                 int* __restrict__ gstart, int* __restrict__ counts,
                                                 u64* __restrict__ zrowA, u64* __restrict__ zrowB) {
  __shared__ int lb[NG + 1];
  int t = threadIdx.x;
  if (t <= NG) {                      // first index with batch[i] >= t (batch is sorted)
    int lo = 0, hi = NN;
    while (lo < hi) { int mid = (lo + hi) >> 1; if (batch[mid] < t) lo = mid + 1; else hi = mid; }
    lb[t] = lo;
  }
  if (t >= 96 && t < 112) zrowA[t - 96] = 0ull;   // 16 u64 = 128 B row NN
  if (t >= 112) zrowB[t - 112] = 0ull;
  __syncthreads();
  if (t < NG) { gstart[t] = lb[t]; counts[t] = lb[t + 1] - lb[t]; }
  if (t == 0) gstart[NG] = NN;
}

__global__ __launch_bounds__(256) void k_hist(const int* __restrict__ ei, int* __restrict__ ghist) {
  __shared__ int h[NB];
  int t = threadIdx.x, blk = blockIdx.x;
  for (int i = t; i < NB; i += 256) h[i] = 0;
  __syncthreads();
  int e0 = blk * EPB, e1 = min(NE, e0 + EPB);
  for (int e = e0 + t; e < e1; e += 256) atomicAdd(&h[ei[NE + e] >> 7], 1);
  __syncthreads();
  for (int i = t; i < NB; i += 256) ghist[i * NBLK + blk] = h[i];
}

__global__ __launch_bounds__(256) void k_scan1g(int* __restrict__ data, int* __restrict__ bsums) {
  __shared__ int sh[256];
  int t = threadIdx.x;
  int base = blockIdx.x * 1024 + t * 4;
  int4 v = *reinterpret_cast<const int4*>(data + base);
  int s = v.x + v.y + v.z + v.w;
  sh[t] = s;
  __syncthreads();
  for (int o = 1; o < 256; o <<= 1) {
    int x = (t >= o) ? sh[t - o] : 0;
    __syncthreads();
    sh[t] += x;
    __syncthreads();
  }
  int ex = sh[t] - s;
  int4 o4;
  o4.x = ex; o4.y = ex + v.x; o4.z = ex + v.x + v.y; o4.w = ex + v.x + v.y + v.z;
  *reinterpret_cast<int4*>(data + base) = o4;
  if (t == 255) bsums[blockIdx.x] = sh[255];
}

__global__ __launch_bounds__(512) void k_scan2(int* bsums, int nb) {
  __shared__ int sh[512];
  int t = threadIdx.x;
  int v = (t < nb) ? bsums[t] : 0;
  sh[t] = v;
  __syncthreads();
  for (int o = 1; o < 512; o <<= 1) {
    int x = (t >= o) ? sh[t - o] : 0;
    __syncthreads();
    sh[t] += x;
    __syncthreads();
  }
  if (t < nb) bsums[t] = sh[t] - v;   // exclusive
}

__global__ __launch_bounds__(256) void k_scan3g(int* __restrict__ data, const int* __restrict__ bsums) {
  int t = threadIdx.x;
  int base = blockIdx.x * 1024 + t * 4;
  int add = bsums[blockIdx.x];
  int4 v = *reinterpret_cast<int4*>(data + base);
  v.x += add; v.y += add; v.z += add; v.w += add;
  *reinterpret_cast<int4*>(data + base) = v;
}

// scatter: pack (dlocal, src) into one int: (d&127)<<17 | s  (s < 2^17)
__global__ __launch_bounds__(256) void k_scatter(const int* __restrict__ ei, const int* __restrict__ ghist,
                                                 int* __restrict__ tmp) {
  __shared__ int cur[NB];
  int t = threadIdx.x, blk = blockIdx.x;
  for (int i = t; i < NB; i += 256) cur[i] = ghist[i * NBLK + blk];
  __syncthreads();
  int e0 = blk * EPB, e1 = min(NE, e0 + EPB);
  for (int e = e0 + t; e < e1; e += 256) {
    int d = ei[NE + e], s = ei[e];
    int p = atomicAdd(&cur[d >> 7], 1);   // LDS atomic (fast, block-local)
    tmp[p] = ((d & 127) << 17) | s;
  }
}

// fine bucket: per-node deg/offs/dis + CSR
__global__ __launch_bounds__(256) void k_fine(const int* __restrict__ tmp, const int* __restrict__ ghist,
                                              int* __restrict__ deg, int* __restrict__ offs,
                                              float* __restrict__ dis, int* __restrict__ csr) {
  __shared__ int fh[128], fsc[128], fc[128];
  int b = blockIdx.x, t = threadIdx.x;
  int bs = ghist[b * NBLK];
  int be = (b + 1 < NB) ? ghist[(b + 1) * NBLK] : NE;
  if (t < 128) fh[t] = 0;
  __syncthreads();
  for (int e = bs + t; e < be; e += 256) atomicAdd(&fh[tmp[e] >> 17], 1);
  __syncthreads();
  if (t < 128) fsc[t] = fh[t];
  __syncthreads();
  for (int o = 1; o < 128; o <<= 1) {
    int x = 0;
    if (t < 128 && t >= o) x = fsc[t - o];
    __syncthreads();
    if (t < 128) fsc[t] += x;
    __syncthreads();
  }
  if (t < 128) {
    int ex = fsc[t] - fh[t];
    int node = b * 128 + t;
    fc[t] = bs + ex;
    if (node < NN) {
      deg[node] = fh[t];
      offs[node] = bs + ex;
      dis[node] = rsqrtf((float)(fh[t] + 1));   // +1 self-loop
    }
  }
  __syncthreads();
  for (int e = bs + t; e < be; e += 256) {
    int v = tmp[e];
    int p = atomicAdd(&fc[v >> 17], 1);
    csr[p] = v & 0x1FFFF;
  }
}

// ---------------- W pre-pack: fragment-major bf16 B-operand (both layers) ----------------
__global__ __launch_bounds__(256) void k_prepw(const float* __restrict__ W1, ushort* __restrict__ WF1,
                                               const float* __restrict__ W2, ushort* __restrict__ WF2) {
  int tt = blockIdx.x * 256 + threadIdx.x;
  if (tt >= 4096) return;
  const float* W = (tt < 2048) ? W1 : W2;
  ushort* WF = (tt < 2048) ? WF1 : WF2;
  int t = tt & 2047;
  int lane = t & 63, nk = t >> 6;
  int n = nk >> 2, ks = nk & 3;
  int col = n * 16 + (lane & 15);
  int k0 = ks * 32 + (lane >> 4) * 8;
#pragma unroll
  for (int j = 0; j < 8; ++j) WF[(size_t)t * 8 + j] = f2b(W[(k0 + j) * NH + col]);
}

// ---------------- MFMA GEMM: hs_fp8 = (norm?(X) @ W) * dis ----------------
// Wave = 16 rows x 128 cols. Block = 4 waves = 64 rows. NORM path reads fp8 A-input.
template <bool NORM>
__global__ __launch_bounds__(256) void k_gemm(const void* __restrict__ Xv, const ushort* __restrict__ WF,
                                              const float* __restrict__ dis, const int* __restrict__ batch,
                                              const float* __restrict__ Aaff, const float* __restrict__ Baff,
                                              uchar* __restrict__ out) {
  __shared__ uint sds[4][512];            // per-wave 2KB fp8 staging
  int t = threadIdx.x;
  int w = t >> 6, lane = t & 63;
  int r0 = blockIdx.x * 64 + w * 16;
  int arow = r0 + (lane & 15);
  int khi = lane >> 4;                    // 0..3
  int arowc = (arow < NN) ? arow : (NN - 1);

  f32x4 acc[8];
#pragma unroll
  for (int n = 0; n < 8; ++n) acc[n] = (f32x4){0.f, 0.f, 0.f, 0.f};

  int g = 0;
  if (NORM) g = batch[arowc];
  const bf16x8* WFv = reinterpret_cast<const bf16x8*>(WF);

#pragma unroll
  for (int ks = 0; ks < 4; ++ks) {
    int k0 = ks * 32 + khi * 8;
    bf16x8 a;
    if (!NORM) {
      const float* X = (const float*)Xv;
      float4 x0 = *reinterpret_cast<const float4*>(X + (size_t)arowc * NH + k0);
      float4 x1 = *reinterpret_cast<const float4*>(X + (size_t)arowc * NH + k0 + 4);
      a[0] = (short)f2b(x0.x); a[1] = (short)f2b(x0.y); a[2] = (short)f2b(x0.z); a[3] = (short)f2b(x0.w);
      a[4] = (short)f2b(x1.x); a[5] = (short)f2b(x1.y); a[6] = (short)f2b(x1.z); a[7] = (short)f2b(x1.w);
    } else {
      const uchar* X8 = (const uchar*)Xv;  // fp8 [node][128]
      u64 v = *reinterpret_cast<const u64*>(X8 + (size_t)arowc * NH + k0);
      uint lo = (uint)v, hi = (uint)(v >> 32);
      f32x2 x01 = __builtin_amdgcn_cvt_pk_f32_fp8((int)lo, false);
      f32x2 x23 = __builtin_amdgcn_cvt_pk_f32_fp8((int)lo, true);
      f32x2 x45 = __builtin_amdgcn_cvt_pk_f32_fp8((int)hi, false);
      f32x2 x67 = __builtin_amdgcn_cvt_pk_f32_fp8((int)hi, true);
      float4 A0 = *reinterpret_cast<const float4*>(Aaff + g * NH + k0);
      float4 A1 = *reinterpret_cast<const float4*>(Aaff + g * NH + k0 + 4);
      float4 B0 = *reinterpret_cast<const float4*>(Baff + g * NH + k0);
      float4 B1 = *reinterpret_cast<const float4*>(Baff + g * NH + k0 + 4);
      a[0] = (short)f2b(fmaf(A0.x, x01[0], B0.x));
      a[1] = (short)f2b(fmaf(A0.y, x01[1], B0.y));
      a[2] = (short)f2b(fmaf(A0.z, x23[0], B0.z));
      a[3] = (short)f2b(fmaf(A0.w, x23[1], B0.w));
      a[4] = (short)f2b(fmaf(A1.x, x45[0], B1.x));
      a[5] = (short)f2b(fmaf(A1.y, x45[1], B1.y));
      a[6] = (short)f2b(fmaf(A1.z, x67[0], B1.z));
      a[7] = (short)f2b(fmaf(A1.w, x67[1], B1.w));
    }
#pragma unroll
    for (int n = 0; n < 8; ++n) {
      bf16x8 b = WFv[(n * 4 + ks) * 64 + lane];
      acc[n] = __builtin_amdgcn_mfma_f32_16x16x32_bf16(a, b, acc[n], 0, 0, 0);
    }
  }

  // epilogue: D (col = n*16 + (lane&15), row = khi*4 + reg) -> fp8 bytes in LDS
  int colb = lane & 15;
  uchar* sb = (uchar*)sds[w];
#pragma unroll
  for (int reg = 0; reg < 4; ++reg) {
    int row = khi * 4 + reg;
    int grow = r0 + row;
    float d = (grow < NN) ? dis[grow] : 0.f;
#pragma unroll
    for (int n = 0; n < 8; n += 2) {
      int p2 = __builtin_amdgcn_cvt_pk_fp8_f32(acc[n][reg] * d, acc[n + 1][reg] * d, 0, false);
      sb[row * 128 + n * 16 + colb] = (uchar)(p2 & 0xFF);
      sb[row * 128 + (n + 1) * 16 + colb] = (uchar)((p2 >> 8) & 0xFF);
    }
  }
  __syncthreads();
  // coalesced write-out: 16 rows x 128B contiguous per wave
  const u64* ss = (const u64*)sds[w];
  u64* gout = (u64*)(out + (size_t)r0 * 128);
#pragma unroll
  for (int it = 0; it < 4; ++it) {
    int idx = it * 64 + lane;
    int row = idx >> 4;
    if (r0 + row < NN) __builtin_nontemporal_store(ss[idx], &gout[idx]);
  }
}

// ---------------- aggregation: t = relu(dis[i]*(hs[i]+sum_src hs[src]) + b), fp8 in/out ----------------
// 1 node/wave; 8 groups of 8 lanes each handle a different edge; lane loads dwordx4 (16 fp8).
// One 32-edge predicated super-batch (all loads issued up front, zero-row NN for invalid slots).
// ACCUM of empty 8-edge sub-batches skipped via wave-uniform branches.
__global__ __launch_bounds__(256) void k_agg(const u64* __restrict__ hf8, const int* __restrict__ offs,
                                             const int* __restrict__ deg, const int* __restrict__ csr,
                                             const float* __restrict__ dis, const float* __restrict__ bias,
                                             u64* __restrict__ outb) {
  int w = threadIdx.x >> 6, lane = threadIdx.x & 63;
  int grp = lane >> 3, sub = lane & 7;
  int node = blockIdx.x * 4 + w;
  if (node >= NN) return;
  const u32x4* rows = reinterpret_cast<const u32x4*>(hf8);
  f32x2 a0 = (f32x2){0.f, 0.f}, a1 = (f32x2){0.f, 0.f}, a2 = (f32x2){0.f, 0.f}, a3 = (f32x2){0.f, 0.f};
  f32x2 a4 = (f32x2){0.f, 0.f}, a5 = (f32x2){0.f, 0.f}, a6 = (f32x2){0.f, 0.f}, a7 = (f32x2){0.f, 0.f};
#define ACCUM(V)                                                       \
  {                                                                    \
    a0 += __builtin_amdgcn_cvt_pk_f32_fp8((int)(V)[0], false);         \
    a1 += __builtin_amdgcn_cvt_pk_f32_fp8((int)(V)[0], true);          \
    a2 += __builtin_amdgcn_cvt_pk_f32_fp8((int)(V)[1], false);         \
    a3 += __builtin_amdgcn_cvt_pk_f32_fp8((int)(V)[1], true);          \
    a4 += __builtin_amdgcn_cvt_pk_f32_fp8((int)(V)[2], false);         \
    a5 += __builtin_amdgcn_cvt_pk_f32_fp8((int)(V)[2], true);          \
    a6 += __builtin_amdgcn_cvt_pk_f32_fp8((int)(V)[3], false);         \
    a7 += __builtin_amdgcn_cvt_pk_f32_fp8((int)(V)[3], true);          \
  }
  int beg = __builtin_nontemporal_load(offs + node);
  int cnt = __builtin_nontemporal_load(deg + node);
  if (grp == 0) {                       // self term counted once (8 lanes cover the row)
    u32x4 v = rows[(size_t)node * 8 + sub];
    ACCUM(v);
  }
  int lim = beg + cnt - 1;
  int i = 0;
  do {                                  // one iteration covers 32 edges (all loads concurrent)
    int p0 = beg + i + grp;
    int c0 = __builtin_nontemporal_load(csr + min(p0, lim));
    int c1 = __builtin_nontemporal_load(csr + min(p0 + 8, lim));
    int c2 = __builtin_nontemporal_load(csr + min(p0 + 16, lim));
    int c3 = __builtin_nontemporal_load(csr + min(p0 + 24, lim));
    int s0 = (p0 <= lim) ? c0 : NN;     // row NN is all zeros
    int s1 = (p0 + 8 <= lim) ? c1 : NN;
    int s2 = (p0 + 16 <= lim) ? c2 : NN;
    int s3 = (p0 + 24 <= lim) ? c3 : NN;
    u32x4 v0 = rows[(size_t)s0 * 8 + sub];
    u32x4 v1 = rows[(size_t)s1 * 8 + sub];
    u32x4 v2 = rows[(size_t)s2 * 8 + sub];
    u32x4 v3 = rows[(size_t)s3 * 8 + sub];
    ACCUM(v0);
    if (cnt > i + 8)  ACCUM(v1);        // wave-uniform skip of empty sub-batches
    if (cnt > i + 16) ACCUM(v2);
    if (cnt > i + 24) ACCUM(v3);
    i += 32;
  } while (i < cnt);
#undef ACCUM
  // combine the 8 groups: lane (grp, sub) holds feats [sub*16, sub*16+16)
  float f[16] = {a0[0], a0[1], a1[0], a1[1], a2[0], a2[1], a3[0], a3[1],
                 a4[0], a4[1], a5[0], a5[1], a6[0], a6[1], a7[0], a7[1]};
#pragma unroll
  for (int k = 0; k < 16; ++k) {
    f[k] += __shfl_xor(f[k], 8);
    f[k] += __shfl_xor(f[k], 16);
    f[k] += __shfl_xor(f[k], 32);
  }
  if (grp == 0) {
    float d = dis[node];
    const float4* bp = reinterpret_cast<const float4*>(bias + sub * 16);
    float bb[16];
#pragma unroll
    for (int k = 0; k < 4; ++k) {
      float4 b4 = bp[k];
      bb[4 * k] = b4.x; bb[4 * k + 1] = b4.y; bb[4 * k + 2] = b4.z; bb[4 * k + 3] = b4.w;
    }
    uint wpk[4];
#pragma unroll
    for (int k = 0; k < 4; ++k) {
      float o0 = fmaxf(fmaf(d, f[4 * k + 0], bb[4 * k + 0]), 0.f);
      float o1 = fmaxf(fmaf(d, f[4 * k + 1], bb[4 * k + 1]), 0.f);
      float o2 = fmaxf(fmaf(d, f[4 * k + 2], bb[4 * k + 2]), 0.f);
      float o3 = fmaxf(fmaf(d, f[4 * k + 3], bb[4 * k + 3]), 0.f);
      wpk[k] = ((uint)__builtin_amdgcn_cvt_pk_fp8_f32(o0, o1, 0, false) & 0xFFFFu) |
               ((uint)__builtin_amdgcn_cvt_pk_fp8_f32(o2, o3, 0, false) << 16);
    }
    u64 lo = (u64)wpk[0] | ((u64)wpk[1] << 32);
    u64 hi = (u64)wpk[2] | ((u64)wpk[3] << 32);
    u64* orow = outb + (size_t)node * 16 + sub * 2;
    __builtin_nontemporal_store(lo, orow);
    __builtin_nontemporal_store(hi, orow + 1);
  }
}

// ---------------- GraphNorm stats: per-(g,f) sum & sumsq partials, fp8 input ----------------
__global__ __launch_bounds__(256) void k_stats(const uint* __restrict__ t8, const int* __restrict__ gstart,
                                               float* __restrict__ acc) {
  int g = blockIdx.x >> 4, s = blockIdx.x & 15;
  int beg = gstart[g], end = gstart[g + 1];
  int j = threadIdx.x & 31, q = threadIdx.x >> 5;   // 32 uints/row (4 feats each), 8 row-groups
  f32x2 s01 = (f32x2){0.f, 0.f}, s23 = (f32x2){0.f, 0.f};
  f32x2 q01 = (f32x2){0.f, 0.f}, q23 = (f32x2){0.f, 0.f};
  for (int n = beg + s * 8 + q; n < end; n += 128) {
    uint v = t8[(size_t)n * 32 + j];
    f32x2 f01 = __builtin_amdgcn_cvt_pk_f32_fp8((int)v, false);
    f32x2 f23 = __builtin_amdgcn_cvt_pk_f32_fp8((int)v, true);
    s01 += f01; s23 += f23;
    q01 += f01 * f01; q23 += f23 * f23;
  }
  __shared__ float shs[256][4];
  __shared__ float shq[256][4];
  int t = threadIdx.x;
  shs[t][0] = s01[0]; shs[t][1] = s01[1]; shs[t][2] = s23[0]; shs[t][3] = s23[1];
  shq[t][0] = q01[0]; shq[t][1] = q01[1]; shq[t][2] = q23[0]; shq[t][3] = q23[1];
  __syncthreads();
  if (q == 0) {
    float sm[4], sq[4];
#pragma unroll
    for (int k = 0; k < 4; ++k) { sm[k] = shs[j][k]; sq[k] = shq[j][k]; }
#pragma unroll
    for (int qq = 1; qq < 8; ++qq) {
      int idx = qq * 32 + j;
#pragma unroll
      for (int k = 0; k < 4; ++k) { sm[k] += shs[idx][k]; sq[k] += shq[idx][k]; }
    }
    int f = j * 4;
    float* dst = acc + (size_t)(s * NG + g) * 2 * NH;
#pragma unroll
    for (int k = 0; k < 4; ++k) { dst[f + k] = sm[k]; dst[NH + f + k] = sq[k]; }
  }
}

__global__ __launch_bounds__(128) void k_fin1(const float* __restrict__ acc, const int* __restrict__ counts,
                                              const float* __restrict__ gw, const float* __restrict__ gb,
                                              const float* __restrict__ ga,
                                              float* __restrict__ Aaff, float* __restrict__ Baff) {
  int g = blockIdx.x, f = threadIdx.x;
  float sum = 0.f, sq = 0.f;
#pragma unroll 4
  for (int s = 0; s < 16; ++s) {
    const float* d = acc + (size_t)(s * NG + g) * 2 * NH;
    sum += d[f];
    sq += d[NH + f];
  }
  float cnt = fmaxf((float)counts[g], 1.f);
  float m = sum / cnt;
  float ex2 = sq / cnt;
  float a = ga[f];
  float var = ex2 - 2.f * a * m * m + a * a * m * m;
  float rstd = rsqrtf(var + EPSV);
  float A = gw[f] * rstd;
  Aaff[g * NH + f] = A;
  Baff[g * NH + f] = gb[f] - A * a * m;
}

// fused layer-2 finalize + classifier head + softmax
__global__ __launch_bounds__(128) void k_fin2head(const float* __restrict__ acc, const int* __restrict__ counts,
                                                  const float* __restrict__ gw, const float* __restrict__ gb,
                                                  const float* __restrict__ ga, const float* __restrict__ Wc,
                                                  const float* __restrict__ bc, float* __restrict__ outp) {
  __shared__ float pool[NH];
  __shared__ float lg[NC];
  int g = blockIdx.x, f = threadIdx.x;
  float sum = 0.f, sq = 0.f;
#pragma unroll 4
  for (int s = 0; s < 16; ++s) {
    const float* d = acc + (size_t)(s * NG + g) * 2 * NH;
    sum += d[f];
    sq += d[NH + f];
  }
  float cnt = fmaxf((float)counts[g], 1.f);
  float m = sum / cnt;
  float ex2 = sq / cnt;
  float a = ga[f];
  float var = ex2 - 2.f * a * m * m + a * a * m * m;
  float rstd = rsqrtf(var + EPSV);
  pool[f] = gw[f] * rstd * (m - a * m) + gb[f];
  __syncthreads();
  if (f < NC) {
    float s = bc[f];
    for (int h = 0; h < NH; ++h) s = fmaf(pool[h], Wc[h * NC + f], s);
    lg[f] = s;
  }
  __syncthreads();
  if (f == 0) {
    float mx = lg[0];
    for (int c = 1; c < NC; ++c) mx = fmaxf(mx, lg[c]);
    float ex[NC];
    float ssum = 0.f;
    for (int c = 0; c < NC; ++c) { ex[c] = __expf(lg[c] - mx); ssum += ex[c]; }
    float inv = 1.f / ssum;
    for (int c = 0; c < NC; ++c) outp[g * NC + c] = ex[c] * inv;
  }
}

// ---------------- launch ----------------
extern "C" void kernel_launch(void* const* d_in, const int* in_sizes, int n_in,
                              void* d_out, int out_size, void* d_ws, size_t ws_size,
                              hipStream_t stream) {
  const float* x   = (const float*)d_in[0];
  const int*   ei  = (const int*)d_in[1];
  const int*   bat = (const int*)d_in[2];
  const float* W1  = (const float*)d_in[3];
  const float* b1  = (const float*)d_in[4];
  const float* gw1 = (const float*)d_in[5];
  const float* gb1 = (const float*)d_in[6];
  const float* ga1 = (const float*)d_in[7];
  const float* W2  = (const float*)d_in[8];
  const float* b2  = (const float*)d_in[9];
  const float* gw2 = (const float*)d_in[10];
  const float* gb2 = (const float*)d_in[11];
  const float* ga2 = (const float*)d_in[12];
  const float* Wc  = (const float*)d_in[13];
  const float* bc  = (const float*)d_in[14];
  float* outp = (float*)d_out;

  char* ws = (char*)d_ws;
  size_t off = 0;
  auto alloc = [&](size_t b) { size_t p = off; off += (b + 255) & ~(size_t)255; return p; };
  int*    deg     = (int*)(ws + alloc((size_t)NN * 4));
  float*  dis     = (float*)(ws + alloc((size_t)NN * 4));
  int*    counts  = (int*)(ws + alloc(NG * 4));
  int*    gstart  = (int*)(ws + alloc((NG + 1) * 4));
  int*    offs    = (int*)(ws + alloc((size_t)NN * 4));
  int*    bsums   = (int*)(ws + alloc(512 * 4));
  int*    csr     = (int*)(ws + alloc((size_t)NE * 4));
  float*  statacc = (float*)(ws + alloc((size_t)16 * NG * 2 * NH * 4));   // 1 MB partials
  float*  Aaff    = (float*)(ws + alloc((size_t)NG * NH * 4));
  float*  Baff    = (float*)(ws + alloc((size_t)NG * NH * 4));
  ushort* WF1     = (ushort*)(ws + alloc((size_t)2048 * 8 * 2));
  ushort* WF2     = (ushort*)(ws + alloc((size_t)2048 * 8 * 2));
  uchar*  bufA    = (uchar*)(ws + alloc((size_t)(NN + 1) * NH));   // fp8 + zero row NN
  uchar*  bufB    = (uchar*)(ws + alloc((size_t)(NN + 1) * NH));   // fp8 + zero row NN
  // sort temps alias bufB (dead until first k_agg write): 6.4 (packed int) + 1.6 MB < 12.8 MB - 128B
  int* tmp   = (int*)bufB;
  int* ghist = (int*)((char*)bufB + (((size_t)NE * 4 + 255) & ~(size_t)255));
  (void)ws_size; (void)in_sizes; (void)n_in; (void)out_size;

  u64* zrowA = (u64*)(bufA + (size_t)NN * NH);
  u64* zrowB = (u64*)(bufB + (size_t)NN * NH);

  // prep: counts/gstart via binary search (batch sorted); CSR via counting sort; zero pad rows
  k_gstart2<<<1, 128, 0, stream>>>(bat, gstart, counts, zrowA, zrowB);
  k_hist<<<NBLK, 256, 0, stream>>>(ei, ghist);
  k_scan1g<<<NSB, 256, 0, stream>>>(ghist, bsums);
  k_scan2<<<1, 512, 0, stream>>>(bsums, NSB);
  k_scan3g<<<NSB, 256, 0, stream>>>(ghist, bsums);
  k_scatter<<<NBLK, 256, 0, stream>>>(ei, ghist, tmp);
  k_fine<<<NB, 256, 0, stream>>>(tmp, ghist, deg, offs, dis, csr);
  k_prepw<<<16, 256, 0, stream>>>(W1, WF1, W2, WF2);

  int gemm_grid = (NN + 63) / 64;   // 1563
  int agg_grid  = (NN + 3) / 4;     // 25000

  // layer 1
  k_gemm<false><<<gemm_grid, 256, 0, stream>>>(x, WF1, dis, bat, nullptr, nullptr, bufA);
  k_agg<<<agg_grid, 256, 0, stream>>>((const u64*)bufA, offs, deg, csr, dis, b1, (u64*)bufB);
  k_stats<<<NG * 16, 256, 0, stream>>>((const uint*)bufB, gstart, statacc);
  k_fin1<<<NG, 128, 0, stream>>>(statacc, counts, gw1, gb1, ga1, Aaff, Baff);

  // layer 2 (norm fused into GEMM A-fragment load, fp8 A-input)
  k_gemm<true><<<gemm_grid, 256, 0, stream>>>(bufB, WF2, dis, bat, Aaff, Baff, bufA);
  k_agg<<<agg_grid, 256, 0, stream>>>((const u64*)bufA, offs, deg, csr, dis, b2, (u64*)bufB);
  k_stats<<<NG * 16, 256, 0, stream>>>((const uint*)bufB, gstart, statacc);
  k_fin2head<<<NG, 128, 0, stream>>>(statacc, counts, gw2, gb2, ga2, Wc, bc, outp);
}

// Round 14
// 221.873 us; speedup vs baseline: 1.1223x; 1.1223x over previous
//
#include <hip/hip_runtime.h>
#include <cstdint>

#define NN 100000
#define NE 1600000
#define NG 64
#define NH 128
#define NC 10
#define EPSV 1e-5f

#define NB 782                       // (NN+127)>>7 coarse buckets (128 nodes each)
#define NBLK 512                     // histogram/scatter blocks
#define EPB ((NE + NBLK - 1) / NBLK) // 3125 edges per block
#define NSCAN (NB * NBLK)            // 400384, divisible by 1024
#define NSB (NSCAN / 1024)           // 391 scan blocks

typedef __attribute__((ext_vector_type(8))) short bf16x8;
typedef __attribute__((ext_vector_type(4))) float f32x4;
typedef __attribute__((ext_vector_type(2))) float f32x2;
typedef unsigned long long u64;
typedef unsigned char uchar;

__device__ __forceinline__ ushort f2b(float f) {
  uint u = __builtin_bit_cast(uint, f);
  u = (u + 0x7FFFu + ((u >> 16) & 1u)) >> 16;
  return (ushort)u;
}
__device__ __forceinline__ float b2f(ushort h) {
  return __builtin_bit_cast(float, ((uint)h) << 16);
}

// ---------------- merged prep: gstart/counts + zero rows (blk 0), W pre-pack (blk 1..16),
//                  coarse histogram (blk 17..528) ----------------
__global__ __launch_bounds__(256) void k_prep0(const int* __restrict__ batch,
                                               int* __restrict__ gstart, int* __restrict__ counts,
                                               u64* __restrict__ zrowA, u64* __restrict__ zrowB,
                                               const float* __restrict__ W1, ushort* __restrict__ WF1,
                                               const float* __restrict__ W2, ushort* __restrict__ WF2,
                                               const int* __restrict__ ei, int* __restrict__ ghist) {
  int b = blockIdx.x;
  if (b == 0) {
    __shared__ int lb[NG + 1];
    int t = threadIdx.x;
    if (t <= NG) {                    // first index with batch[i] >= t (batch is sorted)
      int lo = 0, hi = NN;
      while (lo < hi) { int mid = (lo + hi) >> 1; if (batch[mid] < t) lo = mid + 1; else hi = mid; }
      lb[t] = lo;
    }
    if (t >= 96 && t < 112) zrowA[t - 96] = 0ull;   // 16 u64 = 128 B row NN
    if (t >= 112 && t < 128) zrowB[t - 112] = 0ull;
    __syncthreads();
    if (t < NG) { gstart[t] = lb[t]; counts[t] = lb[t + 1] - lb[t]; }
    if (t == 0) gstart[NG] = NN;
  } else if (b <= 16) {
    int tt = (b - 1) * 256 + threadIdx.x;           // 0..4095
    const float* W = (tt < 2048) ? W1 : W2;
    ushort* WF = (tt < 2048) ? WF1 : WF2;
    int t = tt & 2047;
    int lane = t & 63, nk = t >> 6;
    int n = nk >> 2, ks = nk & 3;
    int col = n * 16 + (lane & 15);
    int k0 = ks * 32 + (lane >> 4) * 8;
#pragma unroll
    for (int j = 0; j < 8; ++j) WF[(size_t)t * 8 + j] = f2b(W[(k0 + j) * NH + col]);
  } else {
    __shared__ int h[NB];
    int t = threadIdx.x, blk = b - 17;              // 0..511
    for (int i = t; i < NB; i += 256) h[i] = 0;
    __syncthreads();
    int e0 = blk * EPB, e1 = min(NE, e0 + EPB);
    for (int e = e0 + t; e < e1; e += 256) atomicAdd(&h[ei[NE + e] >> 7], 1);
    __syncthreads();
    for (int i = t; i < NB; i += 256) ghist[i * NBLK + blk] = h[i];
  }
}

__global__ __launch_bounds__(256) void k_scan1g(int* __restrict__ data, int* __restrict__ bsums) {
  __shared__ int sh[256];
  int t = threadIdx.x;
  int base = blockIdx.x * 1024 + t * 4;
  int4 v = *reinterpret_cast<const int4*>(data + base);
  int s = v.x + v.y + v.z + v.w;
  sh[t] = s;
  __syncthreads();
  for (int o = 1; o < 256; o <<= 1) {
    int x = (t >= o) ? sh[t - o] : 0;
    __syncthreads();
    sh[t] += x;
    __syncthreads();
  }
  int ex = sh[t] - s;
  int4 o4;
  o4.x = ex; o4.y = ex + v.x; o4.z = ex + v.x + v.y; o4.w = ex + v.x + v.y + v.z;
  *reinterpret_cast<int4*>(data + base) = o4;
  if (t == 255) bsums[blockIdx.x] = sh[255];
}

__global__ __launch_bounds__(512) void k_scan2(int* bsums, int nb) {
  __shared__ int sh[512];
  int t = threadIdx.x;
  int v = (t < nb) ? bsums[t] : 0;
  sh[t] = v;
  __syncthreads();
  for (int o = 1; o < 512; o <<= 1) {
    int x = (t >= o) ? sh[t - o] : 0;
    __syncthreads();
    sh[t] += x;
    __syncthreads();
  }
  if (t < nb) bsums[t] = sh[t] - v;   // exclusive
}

__global__ __launch_bounds__(256) void k_scan3g(int* __restrict__ data, const int* __restrict__ bsums) {
  int t = threadIdx.x;
  int base = blockIdx.x * 1024 + t * 4;
  int add = bsums[blockIdx.x];
  int4 v = *reinterpret_cast<int4*>(data + base);
  v.x += add; v.y += add; v.z += add; v.w += add;
  *reinterpret_cast<int4*>(data + base) = v;
}

// scatter: pack (dlocal, src) into one int: (d&127)<<17 | s  (s < 2^17)
__global__ __launch_bounds__(256) void k_scatter(const int* __restrict__ ei, const int* __restrict__ ghist,
                                                 int* __restrict__ tmp) {
  __shared__ int cur[NB];
  int t = threadIdx.x, blk = blockIdx.x;
  for (int i = t; i < NB; i += 256) cur[i] = ghist[i * NBLK + blk];
  __syncthreads();
  int e0 = blk * EPB, e1 = min(NE, e0 + EPB);
  for (int e = e0 + t; e < e1; e += 256) {
    int d = ei[NE + e], s = ei[e];
    int p = atomicAdd(&cur[d >> 7], 1);   // LDS atomic (fast, block-local)
    tmp[p] = ((d & 127) << 17) | s;
  }
}

// fine bucket: per-node deg/offs/dis + CSR
__global__ __launch_bounds__(256) void k_fine(const int* __restrict__ tmp, const int* __restrict__ ghist,
                                              int* __restrict__ deg, int* __restrict__ offs,
                                              float* __restrict__ dis, int* __restrict__ csr) {
  __shared__ int fh[128], fsc[128], fc[128];
  int b = blockIdx.x, t = threadIdx.x;
  int bs = ghist[b * NBLK];
  int be = (b + 1 < NB) ? ghist[(b + 1) * NBLK] : NE;
  if (t < 128) fh[t] = 0;
  __syncthreads();
  for (int e = bs + t; e < be; e += 256) atomicAdd(&fh[tmp[e] >> 17], 1);
  __syncthreads();
  if (t < 128) fsc[t] = fh[t];
  __syncthreads();
  for (int o = 1; o < 128; o <<= 1) {
    int x = 0;
    if (t < 128 && t >= o) x = fsc[t - o];
    __syncthreads();
    if (t < 128) fsc[t] += x;
    __syncthreads();
  }
  if (t < 128) {
    int ex = fsc[t] - fh[t];
    int node = b * 128 + t;
    fc[t] = bs + ex;
    if (node < NN) {
      deg[node] = fh[t];
      offs[node] = bs + ex;
      dis[node] = rsqrtf((float)(fh[t] + 1));   // +1 self-loop
    }
  }
  __syncthreads();
  for (int e = bs + t; e < be; e += 256) {
    int v = tmp[e];
    int p = atomicAdd(&fc[v >> 17], 1);
    csr[p] = v & 0x1FFFF;
  }
}

// ---------------- MFMA GEMM: hs_fp8 = (norm?(X) @ W) * dis ----------------
// Wave = 16 rows x 128 cols. Block = 4 waves = 64 rows. NORM path reads fp8 A-input.
template <bool NORM>
__global__ __launch_bounds__(256) void k_gemm(const void* __restrict__ Xv, const ushort* __restrict__ WF,
                                              const float* __restrict__ dis, const int* __restrict__ batch,
                                              const float* __restrict__ Aaff, const float* __restrict__ Baff,
                                              uchar* __restrict__ out) {
  __shared__ uint sds[4][512];            // per-wave 2KB fp8 staging
  int t = threadIdx.x;
  int w = t >> 6, lane = t & 63;
  int r0 = blockIdx.x * 64 + w * 16;
  int arow = r0 + (lane & 15);
  int khi = lane >> 4;                    // 0..3
  int arowc = (arow < NN) ? arow : (NN - 1);

  f32x4 acc[8];
#pragma unroll
  for (int n = 0; n < 8; ++n) acc[n] = (f32x4){0.f, 0.f, 0.f, 0.f};

  int g = 0;
  if (NORM) g = batch[arowc];
  const bf16x8* WFv = reinterpret_cast<const bf16x8*>(WF);

#pragma unroll
  for (int ks = 0; ks < 4; ++ks) {
    int k0 = ks * 32 + khi * 8;
    bf16x8 a;
    if (!NORM) {
      const float* X = (const float*)Xv;
      float4 x0 = *reinterpret_cast<const float4*>(X + (size_t)arowc * NH + k0);
      float4 x1 = *reinterpret_cast<const float4*>(X + (size_t)arowc * NH + k0 + 4);
      a[0] = (short)f2b(x0.x); a[1] = (short)f2b(x0.y); a[2] = (short)f2b(x0.z); a[3] = (short)f2b(x0.w);
      a[4] = (short)f2b(x1.x); a[5] = (short)f2b(x1.y); a[6] = (short)f2b(x1.z); a[7] = (short)f2b(x1.w);
    } else {
      const uchar* X8 = (const uchar*)Xv;  // fp8 [node][128]
      u64 v = *reinterpret_cast<const u64*>(X8 + (size_t)arowc * NH + k0);
      uint lo = (uint)v, hi = (uint)(v >> 32);
      f32x2 x01 = __builtin_amdgcn_cvt_pk_f32_fp8((int)lo, false);
      f32x2 x23 = __builtin_amdgcn_cvt_pk_f32_fp8((int)lo, true);
      f32x2 x45 = __builtin_amdgcn_cvt_pk_f32_fp8((int)hi, false);
      f32x2 x67 = __builtin_amdgcn_cvt_pk_f32_fp8((int)hi, true);
      float4 A0 = *reinterpret_cast<const float4*>(Aaff + g * NH + k0);
      float4 A1 = *reinterpret_cast<const float4*>(Aaff + g * NH + k0 + 4);
      float4 B0 = *reinterpret_cast<const float4*>(Baff + g * NH + k0);
      float4 B1 = *reinterpret_cast<const float4*>(Baff + g * NH + k0 + 4);
      a[0] = (short)f2b(fmaf(A0.x, x01[0], B0.x));
      a[1] = (short)f2b(fmaf(A0.y, x01[1], B0.y));
      a[2] = (short)f2b(fmaf(A0.z, x23[0], B0.z));
      a[3] = (short)f2b(fmaf(A0.w, x23[1], B0.w));
      a[4] = (short)f2b(fmaf(A1.x, x45[0], B1.x));
      a[5] = (short)f2b(fmaf(A1.y, x45[1], B1.y));
      a[6] = (short)f2b(fmaf(A1.z, x67[0], B1.z));
      a[7] = (short)f2b(fmaf(A1.w, x67[1], B1.w));
    }
#pragma unroll
    for (int n = 0; n < 8; ++n) {
      bf16x8 b = WFv[(n * 4 + ks) * 64 + lane];
      acc[n] = __builtin_amdgcn_mfma_f32_16x16x32_bf16(a, b, acc[n], 0, 0, 0);
    }
  }

  // epilogue: D (col = n*16 + (lane&15), row = khi*4 + reg) -> fp8 bytes in LDS
  int colb = lane & 15;
  uchar* sb = (uchar*)sds[w];
#pragma unroll
  for (int reg = 0; reg < 4; ++reg) {
    int row = khi * 4 + reg;
    int grow = r0 + row;
    float d = (grow < NN) ? dis[grow] : 0.f;
#pragma unroll
    for (int n = 0; n < 8; n += 2) {
      int p2 = __builtin_amdgcn_cvt_pk_fp8_f32(acc[n][reg] * d, acc[n + 1][reg] * d, 0, false);
      sb[row * 128 + n * 16 + colb] = (uchar)(p2 & 0xFF);
      sb[row * 128 + (n + 1) * 16 + colb] = (uchar)((p2 >> 8) & 0xFF);
    }
  }
  __syncthreads();
  // coalesced write-out: 16 rows x 128B contiguous per wave
  const u64* ss = (const u64*)sds[w];
  u64* gout = (u64*)(out + (size_t)r0 * 128);
#pragma unroll
  for (int it = 0; it < 4; ++it) {
    int idx = it * 64 + lane;
    int row = idx >> 4;
    if (r0 + row < NN) __builtin_nontemporal_store(ss[idx], &gout[idx]);
  }
}

// ---------------- aggregation: t = relu(dis[i]*(hs[i]+sum_src hs[src]) + b), fp8 in/out ----------------
// 1 node/wave; 4 groups of 16 lanes handle different edges; lane loads u64 (8 fp8).
// Batch A (edges 0-15) always; batch B (16-31) in wave-uniform branch, loads concurrent with A;
// rare overflow loop for deg>32. Invalid slots read zero row NN.
__global__ __launch_bounds__(256) void k_agg(const u64* __restrict__ hf8, const int* __restrict__ offs,
                                             const int* __restrict__ deg, const int* __restrict__ csr,
                                             const float* __restrict__ dis, const float* __restrict__ bias,
                                             u64* __restrict__ outb) {
  int w = threadIdx.x >> 6, lane = threadIdx.x & 63;
  int grp = lane >> 4, sub = lane & 15;
  int node = blockIdx.x * 4 + w;
  if (node >= NN) return;
  f32x2 a01 = (f32x2){0.f, 0.f}, a23 = (f32x2){0.f, 0.f};
  f32x2 a45 = (f32x2){0.f, 0.f}, a67 = (f32x2){0.f, 0.f};
#define ACCUM(V)                                                          \
  {                                                                       \
    uint lo_ = (uint)(V), hi_ = (uint)((V) >> 32);                        \
    a01 += __builtin_amdgcn_cvt_pk_f32_fp8((int)lo_, false);              \
    a23 += __builtin_amdgcn_cvt_pk_f32_fp8((int)lo_, true);               \
    a45 += __builtin_amdgcn_cvt_pk_f32_fp8((int)hi_, false);              \
    a67 += __builtin_amdgcn_cvt_pk_f32_fp8((int)hi_, true);               \
  }
#define BATCH(IBASE)                                                      \
  {                                                                       \
    int p0 = beg + (IBASE) + grp;                                         \
    int c0 = __builtin_nontemporal_load(csr + min(p0, lim));              \
    int c1 = __builtin_nontemporal_load(csr + min(p0 + 4, lim));          \
    int c2 = __builtin_nontemporal_load(csr + min(p0 + 8, lim));          \
    int c3 = __builtin_nontemporal_load(csr + min(p0 + 12, lim));         \
    int s0 = (p0 <= lim) ? c0 : NN;                                       \
    int s1 = (p0 + 4 <= lim) ? c1 : NN;                                   \
    int s2 = (p0 + 8 <= lim) ? c2 : NN;                                   \
    int s3 = (p0 + 12 <= lim) ? c3 : NN;                                  \
    u64 v0 = hf8[(size_t)s0 * 16 + sub];                                  \
    u64 v1 = hf8[(size_t)s1 * 16 + sub];                                  \
    u64 v2 = hf8[(size_t)s2 * 16 + sub];                                  \
    u64 v3 = hf8[(size_t)s3 * 16 + sub];                                  \
    ACCUM(v0); ACCUM(v1); ACCUM(v2); ACCUM(v3);                           \
  }
  int beg = __builtin_nontemporal_load(offs + node);
  int cnt = __builtin_nontemporal_load(deg + node);
  if (grp == 0) {                       // self term counted once
    u64 v = hf8[(size_t)node * 16 + sub];
    ACCUM(v);
  }
  int lim = beg + cnt - 1;
  BATCH(0);                             // edges 0..15 (predicated)
  if (cnt > 16) {                       // wave-uniform: edges 16..31 concurrent with batch A
    BATCH(16);
    for (int i = 32; i < cnt; i += 16) BATCH(i);   // deg>32: rare
  }
#undef BATCH
#undef ACCUM
  float a0 = a01[0], a1 = a01[1], a2 = a23[0], a3 = a23[1];
  float a4 = a45[0], a5 = a45[1], a6 = a67[0], a7 = a67[1];
  a0 += __shfl_xor(a0, 16); a0 += __shfl_xor(a0, 32);
  a1 += __shfl_xor(a1, 16); a1 += __shfl_xor(a1, 32);
  a2 += __shfl_xor(a2, 16); a2 += __shfl_xor(a2, 32);
  a3 += __shfl_xor(a3, 16); a3 += __shfl_xor(a3, 32);
  a4 += __shfl_xor(a4, 16); a4 += __shfl_xor(a4, 32);
  a5 += __shfl_xor(a5, 16); a5 += __shfl_xor(a5, 32);
  a6 += __shfl_xor(a6, 16); a6 += __shfl_xor(a6, 32);
  a7 += __shfl_xor(a7, 16); a7 += __shfl_xor(a7, 32);
  if (grp == 0) {
    float d = dis[node];
    float4 bA = *reinterpret_cast<const float4*>(bias + sub * 8);
    float4 bB = *reinterpret_cast<const float4*>(bias + sub * 8 + 4);
    float o0 = fmaxf(fmaf(d, a0, bA.x), 0.f);
    float o1 = fmaxf(fmaf(d, a1, bA.y), 0.f);
    float o2 = fmaxf(fmaf(d, a2, bA.z), 0.f);
    float o3 = fmaxf(fmaf(d, a3, bA.w), 0.f);
    float o4 = fmaxf(fmaf(d, a4, bB.x), 0.f);
    float o5 = fmaxf(fmaf(d, a5, bB.y), 0.f);
    float o6 = fmaxf(fmaf(d, a6, bB.z), 0.f);
    float o7 = fmaxf(fmaf(d, a7, bB.w), 0.f);
    uint b01 = (uint)__builtin_amdgcn_cvt_pk_fp8_f32(o0, o1, 0, false) & 0xFFFFu;
    uint b23 = (uint)__builtin_amdgcn_cvt_pk_fp8_f32(o2, o3, 0, false) & 0xFFFFu;
    uint b45 = (uint)__builtin_amdgcn_cvt_pk_fp8_f32(o4, o5, 0, false) & 0xFFFFu;
    uint b67 = (uint)__builtin_amdgcn_cvt_pk_fp8_f32(o6, o7, 0, false) & 0xFFFFu;
    u64 pk = (u64)(b01 | (b23 << 16)) | ((u64)(b45 | (b67 << 16)) << 32);
    __builtin_nontemporal_store(pk, &outb[(size_t)node * 16 + sub]);
  }
}

// ---------------- GraphNorm stats: per-(g,f) sum & sumsq partials, fp8 input ----------------
__global__ __launch_bounds__(256) void k_stats(const uint* __restrict__ t8, const int* __restrict__ gstart,
                                               float* __restrict__ acc) {
  int g = blockIdx.x >> 4, s = blockIdx.x & 15;
  int beg = gstart[g], end = gstart[g + 1];
  int j = threadIdx.x & 31, q = threadIdx.x >> 5;   // 32 uints/row (4 feats each), 8 row-groups
  f32x2 s01 = (f32x2){0.f, 0.f}, s23 = (f32x2){0.f, 0.f};
  f32x2 q01 = (f32x2){0.f, 0.f}, q23 = (f32x2){0.f, 0.f};
  for (int n = beg + s * 8 + q; n < end; n += 128) {
    uint v = t8[(size_t)n * 32 + j];
    f32x2 f01 = __builtin_amdgcn_cvt_pk_f32_fp8((int)v, false);
    f32x2 f23 = __builtin_amdgcn_cvt_pk_f32_fp8((int)v, true);
    s01 += f01; s23 += f23;
    q01 += f01 * f01; q23 += f23 * f23;
  }
  __shared__ float shs[256][4];
  __shared__ float shq[256][4];
  int t = threadIdx.x;
  shs[t][0] = s01[0]; shs[t][1] = s01[1]; shs[t][2] = s23[0]; shs[t][3] = s23[1];
  shq[t][0] = q01[0]; shq[t][1] = q01[1]; shq[t][2] = q23[0]; shq[t][3] = q23[1];
  __syncthreads();
  if (q == 0) {
    float sm[4], sq[4];
#pragma unroll
    for (int k = 0; k < 4; ++k) { sm[k] = shs[j][k]; sq[k] = shq[j][k]; }
#pragma unroll
    for (int qq = 1; qq < 8; ++qq) {
      int idx = qq * 32 + j;
#pragma unroll
      for (int k = 0; k < 4; ++k) { sm[k] += shs[idx][k]; sq[k] += shq[idx][k]; }
    }
    int f = j * 4;
    float* dst = acc + (size_t)(s * NG + g) * 2 * NH;
#pragma unroll
    for (int k = 0; k < 4; ++k) { dst[f + k] = sm[k]; dst[NH + f + k] = sq[k]; }
  }
}

__global__ __launch_bounds__(128) void k_fin1(const float* __restrict__ acc, const int* __restrict__ counts,
                                              const float* __restrict__ gw, const float* __restrict__ gb,
                                              const float* __restrict__ ga,
                                              float* __restrict__ Aaff, float* __restrict__ Baff) {
  int g = blockIdx.x, f = threadIdx.x;
  float sum = 0.f, sq = 0.f;
#pragma unroll 4
  for (int s = 0; s < 16; ++s) {
    const float* d = acc + (size_t)(s * NG + g) * 2 * NH;
    sum += d[f];
    sq += d[NH + f];
  }
  float cnt = fmaxf((float)counts[g], 1.f);
  float m = sum / cnt;
  float ex2 = sq / cnt;
  float a = ga[f];
  float var = ex2 - 2.f * a * m * m + a * a * m * m;
  float rstd = rsqrtf(var + EPSV);
  float A = gw[f] * rstd;
  Aaff[g * NH + f] = A;
  Baff[g * NH + f] = gb[f] - A * a * m;
}

// fused layer-2 finalize + classifier head + softmax
__global__ __launch_bounds__(128) void k_fin2head(const float* __restrict__ acc, const int* __restrict__ counts,
                                                  const float* __restrict__ gw, const float* __restrict__ gb,
                                                  const float* __restrict__ ga, const float* __restrict__ Wc,
                                                  const float* __restrict__ bc, float* __restrict__ outp) {
  __shared__ float pool[NH];
  __shared__ float lg[NC];
  int g = blockIdx.x, f = threadIdx.x;
  float sum = 0.f, sq = 0.f;
#pragma unroll 4
  for (int s = 0; s < 16; ++s) {
    const float* d = acc + (size_t)(s * NG + g) * 2 * NH;
    sum += d[f];
    sq += d[NH + f];
  }
  float cnt = fmaxf((float)counts[g], 1.f);
  float m = sum / cnt;
  float ex2 = sq / cnt;
  float a = ga[f];
  float var = ex2 - 2.f * a * m * m + a * a * m * m;
  float rstd = rsqrtf(var + EPSV);
  pool[f] = gw[f] * rstd * (m - a * m) + gb[f];
  __syncthreads();
  if (f < NC) {
    float s = bc[f];
    for (int h = 0; h < NH; ++h) s = fmaf(pool[h], Wc[h * NC + f], s);
    lg[f] = s;
  }
  __syncthreads();
  if (f == 0) {
    float mx = lg[0];
    for (int c = 1; c < NC; ++c) mx = fmaxf(mx, lg[c]);
    float ex[NC];
    float ssum = 0.f;
    for (int c = 0; c < NC; ++c) { ex[c] = __expf(lg[c] - mx); ssum += ex[c]; }
    float inv = 1.f / ssum;
    for (int c = 0; c < NC; ++c) outp[g * NC + c] = ex[c] * inv;
  }
}

// ---------------- launch ----------------
extern "C" void kernel_launch(void* const* d_in, const int* in_sizes, int n_in,
                              void* d_out, int out_size, void* d_ws, size_t ws_size,
                              hipStream_t stream) {
  const float* x   = (const float*)d_in[0];
  const int*   ei  = (const int*)d_in[1];
  const int*   bat = (const int*)d_in[2];
  const float* W1  = (const float*)d_in[3];
  const float* b1  = (const float*)d_in[4];
  const float* gw1 = (const float*)d_in[5];
  const float* gb1 = (const float*)d_in[6];
  const float* ga1 = (const float*)d_in[7];
  const float* W2  = (const float*)d_in[8];
  const float* b2  = (const float*)d_in[9];
  const float* gw2 = (const float*)d_in[10];
  const float* gb2 = (const float*)d_in[11];
  const float* ga2 = (const float*)d_in[12];
  const float* Wc  = (const float*)d_in[13];
  const float* bc  = (const float*)d_in[14];
  float* outp = (float*)d_out;

  char* ws = (char*)d_ws;
  size_t off = 0;
  auto alloc = [&](size_t b) { size_t p = off; off += (b + 255) & ~(size_t)255; return p; };
  int*    deg     = (int*)(ws + alloc((size_t)NN * 4));
  float*  dis     = (float*)(ws + alloc((size_t)NN * 4));
  int*    counts  = (int*)(ws + alloc(NG * 4));
  int*    gstart  = (int*)(ws + alloc((NG + 1) * 4));
  int*    offs    = (int*)(ws + alloc((size_t)NN * 4));
  int*    bsums   = (int*)(ws + alloc(512 * 4));
  int*    csr     = (int*)(ws + alloc((size_t)NE * 4));
  float*  statacc = (float*)(ws + alloc((size_t)16 * NG * 2 * NH * 4));   // 1 MB partials
  float*  Aaff    = (float*)(ws + alloc((size_t)NG * NH * 4));
  float*  Baff    = (float*)(ws + alloc((size_t)NG * NH * 4));
  ushort* WF1     = (ushort*)(ws + alloc((size_t)2048 * 8 * 2));
  ushort* WF2     = (ushort*)(ws + alloc((size_t)2048 * 8 * 2));
  uchar*  bufA    = (uchar*)(ws + alloc((size_t)(NN + 1) * NH));   // fp8 + zero row NN
  uchar*  bufB    = (uchar*)(ws + alloc((size_t)(NN + 1) * NH));   // fp8 + zero row NN
  // sort temps alias bufB (dead until first k_agg write): 6.4 (packed int) + 1.6 MB < 12.8 MB
  int* tmp   = (int*)bufB;
  int* ghist = (int*)((char*)bufB + (((size_t)NE * 4 + 255) & ~(size_t)255));
  (void)ws_size; (void)in_sizes; (void)n_in; (void)out_size;

  u64* zrowA = (u64*)(bufA + (size_t)NN * NH);
  u64* zrowB = (u64*)(bufB + (size_t)NN * NH);

  // prep (merged): gstart/counts + zero rows + W pre-pack + coarse hist
  k_prep0<<<529, 256, 0, stream>>>(bat, gstart, counts, zrowA, zrowB, W1, WF1, W2, WF2, ei, ghist);
  k_scan1g<<<NSB, 256, 0, stream>>>(ghist, bsums);
  k_scan2<<<1, 512, 0, stream>>>(bsums, NSB);
  k_scan3g<<<NSB, 256, 0, stream>>>(ghist, bsums);
  k_scatter<<<NBLK, 256, 0, stream>>>(ei, ghist, tmp);
  k_fine<<<NB, 256, 0, stream>>>(tmp, ghist, deg, offs, dis, csr);

  int gemm_grid = (NN + 63) / 64;   // 1563
  int agg_grid  = (NN + 3) / 4;     // 25000

  // layer 1
  k_gemm<false><<<gemm_grid, 256, 0, stream>>>(x, WF1, dis, bat, nullptr, nullptr, bufA);
  k_agg<<<agg_grid, 256, 0, stream>>>((const u64*)bufA, offs, deg, csr, dis, b1, (u64*)bufB);
  k_stats<<<NG * 16, 256, 0, stream>>>((const uint*)bufB, gstart, statacc);
  k_fin1<<<NG, 128, 0, stream>>>(statacc, counts, gw1, gb1, ga1, Aaff, Baff);

  // layer 2 (norm fused into GEMM A-fragment load, fp8 A-input)
  k_gemm<true><<<gemm_grid, 256, 0, stream>>>(bufB, WF2, dis, bat, Aaff, Baff, bufA);
  k_agg<<<agg_grid, 256, 0, stream>>>((const u64*)bufA, offs, deg, csr, dis, b2, (u64*)bufB);
  k_stats<<<NG * 16, 256, 0, stream>>>((const uint*)bufB, gstart, statacc);
  k_fin2head<<<NG, 128, 0, stream>>>(statacc, counts, gw2, gb2, ga2, Wc, bc, outp);
}

// Round 15
// 207.693 us; speedup vs baseline: 1.1989x; 1.0683x over previous
//
#include <hip/hip_runtime.h>
#include <cstdint>

#define NN 100000
#define NE 1600000
#define NG 64
#define NH 128
#define NC 10
#define EPSV 1e-5f

#define NB 782                       // (NN+127)>>7 coarse buckets (128 nodes each)
#define NBLK 512                     // histogram/scatter blocks
#define EPB ((NE + NBLK - 1) / NBLK) // 3125 edges per block
#define NSCAN (NB * NBLK)            // 400384, divisible by 1024
#define NSB (NSCAN / 1024)           // 391 scan blocks

typedef __attribute__((ext_vector_type(8))) short bf16x8;
typedef __attribute__((ext_vector_type(4))) float f32x4;
typedef __attribute__((ext_vector_type(2))) float f32x2;
typedef unsigned long long u64;
typedef unsigned char uchar;

__device__ __forceinline__ ushort f2b(float f) {
  uint u = __builtin_bit_cast(uint, f);
  u = (u + 0x7FFFu + ((u >> 16) & 1u)) >> 16;
  return (ushort)u;
}
__device__ __forceinline__ float b2f(ushort h) {
  return __builtin_bit_cast(float, ((uint)h) << 16);
}

// ---------------- merged prep: gstart/counts + zero rows (blk 0), W pre-pack (blk 1..16),
//                  coarse histogram (blk 17..528) ----------------
__global__ __launch_bounds__(256) void k_prep0(const int* __restrict__ batch,
                                               int* __restrict__ gstart, int* __restrict__ counts,
                                               u64* __restrict__ zrowA, u64* __restrict__ zrowB,
                                               const float* __restrict__ W1, ushort* __restrict__ WF1,
                                               const float* __restrict__ W2, ushort* __restrict__ WF2,
                                               const int* __restrict__ ei, int* __restrict__ ghist) {
  int b = blockIdx.x;
  if (b == 0) {
    __shared__ int lb[NG + 1];
    int t = threadIdx.x;
    if (t <= NG) {                    // first index with batch[i] >= t (batch is sorted)
      int lo = 0, hi = NN;
      while (lo < hi) { int mid = (lo + hi) >> 1; if (batch[mid] < t) lo = mid + 1; else hi = mid; }
      lb[t] = lo;
    }
    if (t >= 96 && t < 112) zrowA[t - 96] = 0ull;   // 16 u64 = 128 B row NN
    if (t >= 112 && t < 128) zrowB[t - 112] = 0ull;
    __syncthreads();
    if (t < NG) { gstart[t] = lb[t]; counts[t] = lb[t + 1] - lb[t]; }
    if (t == 0) gstart[NG] = NN;
  } else if (b <= 16) {
    int tt = (b - 1) * 256 + threadIdx.x;           // 0..4095
    const float* W = (tt < 2048) ? W1 : W2;
    ushort* WF = (tt < 2048) ? WF1 : WF2;
    int t = tt & 2047;
    int lane = t & 63, nk = t >> 6;
    int n = nk >> 2, ks = nk & 3;
    int col = n * 16 + (lane & 15);
    int k0 = ks * 32 + (lane >> 4) * 8;
#pragma unroll
    for (int j = 0; j < 8; ++j) WF[(size_t)t * 8 + j] = f2b(W[(k0 + j) * NH + col]);
  } else {
    __shared__ int h[NB];
    int t = threadIdx.x, blk = b - 17;              // 0..511
    for (int i = t; i < NB; i += 256) h[i] = 0;
    __syncthreads();
    int e0 = blk * EPB, e1 = min(NE, e0 + EPB);
    for (int e = e0 + t; e < e1; e += 256) atomicAdd(&h[ei[NE + e] >> 7], 1);
    __syncthreads();
    for (int i = t; i < NB; i += 256) ghist[i * NBLK + blk] = h[i];
  }
}

__global__ __launch_bounds__(256) void k_scan1g(int* __restrict__ data, int* __restrict__ bsums) {
  __shared__ int sh[256];
  int t = threadIdx.x;
  int base = blockIdx.x * 1024 + t * 4;
  int4 v = *reinterpret_cast<const int4*>(data + base);
  int s = v.x + v.y + v.z + v.w;
  sh[t] = s;
  __syncthreads();
  for (int o = 1; o < 256; o <<= 1) {
    int x = (t >= o) ? sh[t - o] : 0;
    __syncthreads();
    sh[t] += x;
    __syncthreads();
  }
  int ex = sh[t] - s;
  int4 o4;
  o4.x = ex; o4.y = ex + v.x; o4.z = ex + v.x + v.y; o4.w = ex + v.x + v.y + v.z;
  *reinterpret_cast<int4*>(data + base) = o4;
  if (t == 255) bsums[blockIdx.x] = sh[255];
}

__global__ __launch_bounds__(512) void k_scan2(int* bsums, int nb) {
  __shared__ int sh[512];
  int t = threadIdx.x;
  int v = (t < nb) ? bsums[t] : 0;
  sh[t] = v;
  __syncthreads();
  for (int o = 1; o < 512; o <<= 1) {
    int x = (t >= o) ? sh[t - o] : 0;
    __syncthreads();
    sh[t] += x;
    __syncthreads();
  }
  if (t < nb) bsums[t] = sh[t] - v;   // exclusive
}

// scatter: pack (dlocal, src) into one int: (d&127)<<17 | s  (s < 2^17)
// ghist holds per-1024-chunk exclusive scans; global offset = ghist[idx] + bsums[idx>>10]
__global__ __launch_bounds__(256) void k_scatter(const int* __restrict__ ei, const int* __restrict__ ghist,
                                                 const int* __restrict__ bsums, int* __restrict__ tmp) {
  __shared__ int cur[NB];
  int t = threadIdx.x, blk = blockIdx.x;
  for (int i = t; i < NB; i += 256) {
    int idx = i * NBLK + blk;
    cur[i] = ghist[idx] + bsums[idx >> 10];
  }
  __syncthreads();
  int e0 = blk * EPB, e1 = min(NE, e0 + EPB);
  for (int e = e0 + t; e < e1; e += 256) {
    int d = ei[NE + e], s = ei[e];
    int p = atomicAdd(&cur[d >> 7], 1);   // LDS atomic (fast, block-local)
    tmp[p] = ((d & 127) << 17) | s;
  }
}

// fine bucket: per-node deg/offs/dis + CSR
__global__ __launch_bounds__(256) void k_fine(const int* __restrict__ tmp, const int* __restrict__ ghist,
                                              const int* __restrict__ bsums,
                                              int* __restrict__ deg, int* __restrict__ offs,
                                              float* __restrict__ dis, int* __restrict__ csr) {
  __shared__ int fh[128], fsc[128], fc[128];
  int b = blockIdx.x, t = threadIdx.x;
  int idx0 = b * NBLK;
  int bs = ghist[idx0] + bsums[idx0 >> 10];
  int be = NE;
  if (b + 1 < NB) {
    int idx1 = (b + 1) * NBLK;
    be = ghist[idx1] + bsums[idx1 >> 10];
  }
  if (t < 128) fh[t] = 0;
  __syncthreads();
  for (int e = bs + t; e < be; e += 256) atomicAdd(&fh[tmp[e] >> 17], 1);
  __syncthreads();
  if (t < 128) fsc[t] = fh[t];
  __syncthreads();
  for (int o = 1; o < 128; o <<= 1) {
    int x = 0;
    if (t < 128 && t >= o) x = fsc[t - o];
    __syncthreads();
    if (t < 128) fsc[t] += x;
    __syncthreads();
  }
  if (t < 128) {
    int ex = fsc[t] - fh[t];
    int node = b * 128 + t;
    fc[t] = bs + ex;
    if (node < NN) {
      deg[node] = fh[t];
      offs[node] = bs + ex;
      dis[node] = rsqrtf((float)(fh[t] + 1));   // +1 self-loop
    }
  }
  __syncthreads();
  for (int e = bs + t; e < be; e += 256) {
    int v = tmp[e];
    int p = atomicAdd(&fc[v >> 17], 1);
    csr[p] = v & 0x1FFFF;
  }
}

// ---------------- MFMA GEMM: hs_fp8 = (norm?(X) @ W) * dis ----------------
// Wave = 16 rows x 128 cols. Block = 4 waves = 64 rows. NORM path reads fp8 A-input.
template <bool NORM>
__global__ __launch_bounds__(256) void k_gemm(const void* __restrict__ Xv, const ushort* __restrict__ WF,
                                              const float* __restrict__ dis, const int* __restrict__ batch,
                                              const float* __restrict__ Aaff, const float* __restrict__ Baff,
                                              uchar* __restrict__ out) {
  __shared__ uint sds[4][512];            // per-wave 2KB fp8 staging
  int t = threadIdx.x;
  int w = t >> 6, lane = t & 63;
  int r0 = blockIdx.x * 64 + w * 16;
  int arow = r0 + (lane & 15);
  int khi = lane >> 4;                    // 0..3
  int arowc = (arow < NN) ? arow : (NN - 1);

  f32x4 acc[8];
#pragma unroll
  for (int n = 0; n < 8; ++n) acc[n] = (f32x4){0.f, 0.f, 0.f, 0.f};

  int g = 0;
  if (NORM) g = batch[arowc];
  const bf16x8* WFv = reinterpret_cast<const bf16x8*>(WF);

#pragma unroll
  for (int ks = 0; ks < 4; ++ks) {
    int k0 = ks * 32 + khi * 8;
    bf16x8 a;
    if (!NORM) {
      const float* X = (const float*)Xv;
      float4 x0 = *reinterpret_cast<const float4*>(X + (size_t)arowc * NH + k0);
      float4 x1 = *reinterpret_cast<const float4*>(X + (size_t)arowc * NH + k0 + 4);
      a[0] = (short)f2b(x0.x); a[1] = (short)f2b(x0.y); a[2] = (short)f2b(x0.z); a[3] = (short)f2b(x0.w);
      a[4] = (short)f2b(x1.x); a[5] = (short)f2b(x1.y); a[6] = (short)f2b(x1.z); a[7] = (short)f2b(x1.w);
    } else {
      const uchar* X8 = (const uchar*)Xv;  // fp8 [node][128]
      u64 v = *reinterpret_cast<const u64*>(X8 + (size_t)arowc * NH + k0);
      uint lo = (uint)v, hi = (uint)(v >> 32);
      f32x2 x01 = __builtin_amdgcn_cvt_pk_f32_fp8((int)lo, false);
      f32x2 x23 = __builtin_amdgcn_cvt_pk_f32_fp8((int)lo, true);
      f32x2 x45 = __builtin_amdgcn_cvt_pk_f32_fp8((int)hi, false);
      f32x2 x67 = __builtin_amdgcn_cvt_pk_f32_fp8((int)hi, true);
      float4 A0 = *reinterpret_cast<const float4*>(Aaff + g * NH + k0);
      float4 A1 = *reinterpret_cast<const float4*>(Aaff + g * NH + k0 + 4);
      float4 B0 = *reinterpret_cast<const float4*>(Baff + g * NH + k0);
      float4 B1 = *reinterpret_cast<const float4*>(Baff + g * NH + k0 + 4);
      a[0] = (short)f2b(fmaf(A0.x, x01[0], B0.x));
      a[1] = (short)f2b(fmaf(A0.y, x01[1], B0.y));
      a[2] = (short)f2b(fmaf(A0.z, x23[0], B0.z));
      a[3] = (short)f2b(fmaf(A0.w, x23[1], B0.w));
      a[4] = (short)f2b(fmaf(A1.x, x45[0], B1.x));
      a[5] = (short)f2b(fmaf(A1.y, x45[1], B1.y));
      a[6] = (short)f2b(fmaf(A1.z, x67[0], B1.z));
      a[7] = (short)f2b(fmaf(A1.w, x67[1], B1.w));
    }
#pragma unroll
    for (int n = 0; n < 8; ++n) {
      bf16x8 b = WFv[(n * 4 + ks) * 64 + lane];
      acc[n] = __builtin_amdgcn_mfma_f32_16x16x32_bf16(a, b, acc[n], 0, 0, 0);
    }
  }

  // epilogue: D (col = n*16 + (lane&15), row = khi*4 + reg) -> fp8 bytes in LDS
  int colb = lane & 15;
  uchar* sb = (uchar*)sds[w];
#pragma unroll
  for (int reg = 0; reg < 4; ++reg) {
    int row = khi * 4 + reg;
    int grow = r0 + row;
    float d = (grow < NN) ? dis[grow] : 0.f;
#pragma unroll
    for (int n = 0; n < 8; n += 2) {
      int p2 = __builtin_amdgcn_cvt_pk_fp8_f32(acc[n][reg] * d, acc[n + 1][reg] * d, 0, false);
      sb[row * 128 + n * 16 + colb] = (uchar)(p2 & 0xFF);
      sb[row * 128 + (n + 1) * 16 + colb] = (uchar)((p2 >> 8) & 0xFF);
    }
  }
  __syncthreads();
  // coalesced write-out: 16 rows x 128B contiguous per wave
  const u64* ss = (const u64*)sds[w];
  u64* gout = (u64*)(out + (size_t)r0 * 128);
#pragma unroll
  for (int it = 0; it < 4; ++it) {
    int idx = it * 64 + lane;
    int row = idx >> 4;
    if (r0 + row < NN) __builtin_nontemporal_store(ss[idx], &gout[idx]);
  }
}

// ---------------- aggregation: t = relu(dis[i]*(hs[i]+sum_src hs[src]) + b), fp8 in/out ----------------
// TWO nodes per wave (NN % 8 == 0 so both always valid); 4 groups of 16 lanes per batch.
// Both nodes' batch-A loads issue up front (2 independent chains). Invalid slots -> zero row NN.
__global__ __launch_bounds__(256) void k_agg(const u64* __restrict__ hf8, const int* __restrict__ offs,
                                             const int* __restrict__ deg, const int* __restrict__ csr,
                                             const float* __restrict__ dis, const float* __restrict__ bias,
                                             u64* __restrict__ outb) {
  int w = threadIdx.x >> 6, lane = threadIdx.x & 63;
  int grp = lane >> 4, sub = lane & 15;
  int n0 = (blockIdx.x * 4 + w) * 2;
  int n1 = n0 + 1;                       // always < NN (NN divisible by 8)
  f32x2 A01 = (f32x2){0.f, 0.f}, A23 = (f32x2){0.f, 0.f};
  f32x2 A45 = (f32x2){0.f, 0.f}, A67 = (f32x2){0.f, 0.f};
  f32x2 B01 = (f32x2){0.f, 0.f}, B23 = (f32x2){0.f, 0.f};
  f32x2 B45 = (f32x2){0.f, 0.f}, B67 = (f32x2){0.f, 0.f};
#define ACCUMA(V)                                                         \
  {                                                                       \
    uint lo_ = (uint)(V), hi_ = (uint)((V) >> 32);                        \
    A01 += __builtin_amdgcn_cvt_pk_f32_fp8((int)lo_, false);              \
    A23 += __builtin_amdgcn_cvt_pk_f32_fp8((int)lo_, true);               \
    A45 += __builtin_amdgcn_cvt_pk_f32_fp8((int)hi_, false);              \
    A67 += __builtin_amdgcn_cvt_pk_f32_fp8((int)hi_, true);               \
  }
#define ACCUMB(V)                                                         \
  {                                                                       \
    uint lo_ = (uint)(V), hi_ = (uint)((V) >> 32);                        \
    B01 += __builtin_amdgcn_cvt_pk_f32_fp8((int)lo_, false);              \
    B23 += __builtin_amdgcn_cvt_pk_f32_fp8((int)lo_, true);               \
    B45 += __builtin_amdgcn_cvt_pk_f32_fp8((int)hi_, false);              \
    B67 += __builtin_amdgcn_cvt_pk_f32_fp8((int)hi_, true);               \
  }
#define BATCHA(IBASE)                                                     \
  {                                                                       \
    int p0 = beg0 + (IBASE) + grp;                                        \
    int la = max(lim0, 0);                                                \
    int c0 = __builtin_nontemporal_load(csr + min(p0, la));               \
    int c1 = __builtin_nontemporal_load(csr + min(p0 + 4, la));           \
    int c2 = __builtin_nontemporal_load(csr + min(p0 + 8, la));           \
    int c3 = __builtin_nontemporal_load(csr + min(p0 + 12, la));          \
    int s0 = (p0 <= lim0) ? c0 : NN;                                      \
    int s1 = (p0 + 4 <= lim0) ? c1 : NN;                                  \
    int s2 = (p0 + 8 <= lim0) ? c2 : NN;                                  \
    int s3 = (p0 + 12 <= lim0) ? c3 : NN;                                 \
    u64 v0 = hf8[(size_t)s0 * 16 + sub];                                  \
    u64 v1 = hf8[(size_t)s1 * 16 + sub];                                  \
    u64 v2 = hf8[(size_t)s2 * 16 + sub];                                  \
    u64 v3 = hf8[(size_t)s3 * 16 + sub];                                  \
    ACCUMA(v0); ACCUMA(v1); ACCUMA(v2); ACCUMA(v3);                       \
  }
#define BATCHB(IBASE)                                                     \
  {                                                                       \
    int p0 = beg1 + (IBASE) + grp;                                        \
    int la = max(lim1, 0);                                                \
    int c0 = __builtin_nontemporal_load(csr + min(p0, la));               \
    int c1 = __builtin_nontemporal_load(csr + min(p0 + 4, la));           \
    int c2 = __builtin_nontemporal_load(csr + min(p0 + 8, la));           \
    int c3 = __builtin_nontemporal_load(csr + min(p0 + 12, la));          \
    int s0 = (p0 <= lim1) ? c0 : NN;                                      \
    int s1 = (p0 + 4 <= lim1) ? c1 : NN;                                  \
    int s2 = (p0 + 8 <= lim1) ? c2 : NN;                                  \
    int s3 = (p0 + 12 <= lim1) ? c3 : NN;                                 \
    u64 v0 = hf8[(size_t)s0 * 16 + sub];                                  \
    u64 v1 = hf8[(size_t)s1 * 16 + sub];                                  \
    u64 v2 = hf8[(size_t)s2 * 16 + sub];                                  \
    u64 v3 = hf8[(size_t)s3 * 16 + sub];                                  \
    ACCUMB(v0); ACCUMB(v1); ACCUMB(v2); ACCUMB(v3);                       \
  }
  int beg0 = __builtin_nontemporal_load(offs + n0);
  int cnt0 = __builtin_nontemporal_load(deg + n0);
  int beg1 = __builtin_nontemporal_load(offs + n1);
  int cnt1 = __builtin_nontemporal_load(deg + n1);
  if (grp == 0) {                       // self terms, parallel across groups
    u64 v = hf8[(size_t)n0 * 16 + sub];
    ACCUMA(v);
  }
  if (grp == 1) {
    u64 v = hf8[(size_t)n1 * 16 + sub];
    ACCUMB(v);
  }
  int lim0 = beg0 + cnt0 - 1;
  int lim1 = beg1 + cnt1 - 1;
  BATCHA(0);                            // both nodes' first batches: loads concurrent
  BATCHB(0);
  if (cnt0 > 16) {
    BATCHA(16);
    for (int i = 32; i < cnt0; i += 16) BATCHA(i);
  }
  if (cnt1 > 16) {
    BATCHB(16);
    for (int i = 32; i < cnt1; i += 16) BATCHB(i);
  }
#undef BATCHA
#undef BATCHB
#undef ACCUMA
#undef ACCUMB
  float fA[8] = {A01[0], A01[1], A23[0], A23[1], A45[0], A45[1], A67[0], A67[1]};
  float fB[8] = {B01[0], B01[1], B23[0], B23[1], B45[0], B45[1], B67[0], B67[1]};
#pragma unroll
  for (int k = 0; k < 8; ++k) {
    fA[k] += __shfl_xor(fA[k], 16); fA[k] += __shfl_xor(fA[k], 32);
    fB[k] += __shfl_xor(fB[k], 16); fB[k] += __shfl_xor(fB[k], 32);
  }
  if (grp <= 1) {                       // grp0 stores node0, grp1 stores node1 (parallel)
    int node = (grp == 0) ? n0 : n1;
    const float* fp = (grp == 0) ? fA : fB;
    float d = dis[node];
    float4 bA = *reinterpret_cast<const float4*>(bias + sub * 8);
    float4 bB = *reinterpret_cast<const float4*>(bias + sub * 8 + 4);
    float o0 = fmaxf(fmaf(d, fp[0], bA.x), 0.f);
    float o1 = fmaxf(fmaf(d, fp[1], bA.y), 0.f);
    float o2 = fmaxf(fmaf(d, fp[2], bA.z), 0.f);
    float o3 = fmaxf(fmaf(d, fp[3], bA.w), 0.f);
    float o4 = fmaxf(fmaf(d, fp[4], bB.x), 0.f);
    float o5 = fmaxf(fmaf(d, fp[5], bB.y), 0.f);
    float o6 = fmaxf(fmaf(d, fp[6], bB.z), 0.f);
    float o7 = fmaxf(fmaf(d, fp[7], bB.w), 0.f);
    uint b01 = (uint)__builtin_amdgcn_cvt_pk_fp8_f32(o0, o1, 0, false) & 0xFFFFu;
    uint b23 = (uint)__builtin_amdgcn_cvt_pk_fp8_f32(o2, o3, 0, false) & 0xFFFFu;
    uint b45 = (uint)__builtin_amdgcn_cvt_pk_fp8_f32(o4, o5, 0, false) & 0xFFFFu;
    uint b67 = (uint)__builtin_amdgcn_cvt_pk_fp8_f32(o6, o7, 0, false) & 0xFFFFu;
    u64 pk = (u64)(b01 | (b23 << 16)) | ((u64)(b45 | (b67 << 16)) << 32);
    __builtin_nontemporal_store(pk, &outb[(size_t)node * 16 + sub]);
  }
}

// ---------------- GraphNorm stats: per-(g,f) sum & sumsq partials, fp8 input ----------------
__global__ __launch_bounds__(256) void k_stats(const uint* __restrict__ t8, const int* __restrict__ gstart,
                                               float* __restrict__ acc) {
  int g = blockIdx.x >> 4, s = blockIdx.x & 15;
  int beg = gstart[g], end = gstart[g + 1];
  int j = threadIdx.x & 31, q = threadIdx.x >> 5;   // 32 uints/row (4 feats each), 8 row-groups
  f32x2 s01 = (f32x2){0.f, 0.f}, s23 = (f32x2){0.f, 0.f};
  f32x2 q01 = (f32x2){0.f, 0.f}, q23 = (f32x2){0.f, 0.f};
  for (int n = beg + s * 8 + q; n < end; n += 128) {
    uint v = t8[(size_t)n * 32 + j];
    f32x2 f01 = __builtin_amdgcn_cvt_pk_f32_fp8((int)v, false);
    f32x2 f23 = __builtin_amdgcn_cvt_pk_f32_fp8((int)v, true);
    s01 += f01; s23 += f23;
    q01 += f01 * f01; q23 += f23 * f23;
  }
  __shared__ float shs[256][4];
  __shared__ float shq[256][4];
  int t = threadIdx.x;
  shs[t][0] = s01[0]; shs[t][1] = s01[1]; shs[t][2] = s23[0]; shs[t][3] = s23[1];
  shq[t][0] = q01[0]; shq[t][1] = q01[1]; shq[t][2] = q23[0]; shq[t][3] = q23[1];
  __syncthreads();
  if (q == 0) {
    float sm[4], sq[4];
#pragma unroll
    for (int k = 0; k < 4; ++k) { sm[k] = shs[j][k]; sq[k] = shq[j][k]; }
#pragma unroll
    for (int qq = 1; qq < 8; ++qq) {
      int idx = qq * 32 + j;
#pragma unroll
      for (int k = 0; k < 4; ++k) { sm[k] += shs[idx][k]; sq[k] += shq[idx][k]; }
    }
    int f = j * 4;
    float* dst = acc + (size_t)(s * NG + g) * 2 * NH;
#pragma unroll
    for (int k = 0; k < 4; ++k) { dst[f + k] = sm[k]; dst[NH + f + k] = sq[k]; }
  }
}

__global__ __launch_bounds__(128) void k_fin1(const float* __restrict__ acc, const int* __restrict__ counts,
                                              const float* __restrict__ gw, const float* __restrict__ gb,
                                              const float* __restrict__ ga,
                                              float* __restrict__ Aaff, float* __restrict__ Baff) {
  int g = blockIdx.x, f = threadIdx.x;
  float sum = 0.f, sq = 0.f;
#pragma unroll 4
  for (int s = 0; s < 16; ++s) {
    const float* d = acc + (size_t)(s * NG + g) * 2 * NH;
    sum += d[f];
    sq += d[NH + f];
  }
  float cnt = fmaxf((float)counts[g], 1.f);
  float m = sum / cnt;
  float ex2 = sq / cnt;
  float a = ga[f];
  float var = ex2 - 2.f * a * m * m + a * a * m * m;
  float rstd = rsqrtf(var + EPSV);
  float A = gw[f] * rstd;
  Aaff[g * NH + f] = A;
  Baff[g * NH + f] = gb[f] - A * a * m;
}

// fused layer-2 finalize + classifier head + softmax
__global__ __launch_bounds__(128) void k_fin2head(const float* __restrict__ acc, const int* __restrict__ counts,
                                                  const float* __restrict__ gw, const float* __restrict__ gb,
                                                  const float* __restrict__ ga, const float* __restrict__ Wc,
                                                  const float* __restrict__ bc, float* __restrict__ outp) {
  __shared__ float pool[NH];
  __shared__ float lg[NC];
  int g = blockIdx.x, f = threadIdx.x;
  float sum = 0.f, sq = 0.f;
#pragma unroll 4
  for (int s = 0; s < 16; ++s) {
    const float* d = acc + (size_t)(s * NG + g) * 2 * NH;
    sum += d[f];
    sq += d[NH + f];
  }
  float cnt = fmaxf((float)counts[g], 1.f);
  float m = sum / cnt;
  float ex2 = sq / cnt;
  float a = ga[f];
  float var = ex2 - 2.f * a * m * m + a * a * m * m;
  float rstd = rsqrtf(var + EPSV);
  pool[f] = gw[f] * rstd * (m - a * m) + gb[f];
  __syncthreads();
  if (f < NC) {
    float s = bc[f];
    for (int h = 0; h < NH; ++h) s = fmaf(pool[h], Wc[h * NC + f], s);
    lg[f] = s;
  }
  __syncthreads();
  if (f == 0) {
    float mx = lg[0];
    for (int c = 1; c < NC; ++c) mx = fmaxf(mx, lg[c]);
    float ex[NC];
    float ssum = 0.f;
    for (int c = 0; c < NC; ++c) { ex[c] = __expf(lg[c] - mx); ssum += ex[c]; }
    float inv = 1.f / ssum;
    for (int c = 0; c < NC; ++c) outp[g * NC + c] = ex[c] * inv;
  }
}

// ---------------- launch ----------------
extern "C" void kernel_launch(void* const* d_in, const int* in_sizes, int n_in,
                              void* d_out, int out_size, void* d_ws, size_t ws_size,
                              hipStream_t stream) {
  const float* x   = (const float*)d_in[0];
  const int*   ei  = (const int*)d_in[1];
  const int*   bat = (const int*)d_in[2];
  const float* W1  = (const float*)d_in[3];
  const float* b1  = (const float*)d_in[4];
  const float* gw1 = (const float*)d_in[5];
  const float* gb1 = (const float*)d_in[6];
  const float* ga1 = (const float*)d_in[7];
  const float* W2  = (const float*)d_in[8];
  const float* b2  = (const float*)d_in[9];
  const float* gw2 = (const float*)d_in[10];
  const float* gb2 = (const float*)d_in[11];
  const float* ga2 = (const float*)d_in[12];
  const float* Wc  = (const float*)d_in[13];
  const float* bc  = (const float*)d_in[14];
  float* outp = (float*)d_out;

  char* ws = (char*)d_ws;
  size_t off = 0;
  auto alloc = [&](size_t b) { size_t p = off; off += (b + 255) & ~(size_t)255; return p; };
  int*    deg     = (int*)(ws + alloc((size_t)NN * 4));
  float*  dis     = (float*)(ws + alloc((size_t)NN * 4));
  int*    counts  = (int*)(ws + alloc(NG * 4));
  int*    gstart  = (int*)(ws + alloc((NG + 1) * 4));
  int*    offs    = (int*)(ws + alloc((size_t)NN * 4));
  int*    bsums   = (int*)(ws + alloc(512 * 4));
  int*    csr     = (int*)(ws + alloc((size_t)NE * 4));
  float*  statacc = (float*)(ws + alloc((size_t)16 * NG * 2 * NH * 4));   // 1 MB partials
  float*  Aaff    = (float*)(ws + alloc((size_t)NG * NH * 4));
  float*  Baff    = (float*)(ws + alloc((size_t)NG * NH * 4));
  ushort* WF1     = (ushort*)(ws + alloc((size_t)2048 * 8 * 2));
  ushort* WF2     = (ushort*)(ws + alloc((size_t)2048 * 8 * 2));
  uchar*  bufA    = (uchar*)(ws + alloc((size_t)(NN + 1) * NH));   // fp8 + zero row NN
  uchar*  bufB    = (uchar*)(ws + alloc((size_t)(NN + 1) * NH));   // fp8 + zero row NN
  // sort temps alias bufB (dead until first k_agg write): 6.4 (packed int) + 1.6 MB < 12.8 MB
  int* tmp   = (int*)bufB;
  int* ghist = (int*)((char*)bufB + (((size_t)NE * 4 + 255) & ~(size_t)255));
  (void)ws_size; (void)in_sizes; (void)n_in; (void)out_size;

  u64* zrowA = (u64*)(bufA + (size_t)NN * NH);
  u64* zrowB = (u64*)(bufB + (size_t)NN * NH);

  // prep (merged): gstart/counts + zero rows + W pre-pack + coarse hist
  k_prep0<<<529, 256, 0, stream>>>(bat, gstart, counts, zrowA, zrowB, W1, WF1, W2, WF2, ei, ghist);
  k_scan1g<<<NSB, 256, 0, stream>>>(ghist, bsums);
  k_scan2<<<1, 512, 0, stream>>>(bsums, NSB);
  k_scatter<<<NBLK, 256, 0, stream>>>(ei, ghist, bsums, tmp);
  k_fine<<<NB, 256, 0, stream>>>(tmp, ghist, bsums, deg, offs, dis, csr);

  int gemm_grid = (NN + 63) / 64;   // 1563
  int agg_grid  = NN / 8;           // 12500 (2 nodes per wave)

  // layer 1
  k_gemm<false><<<gemm_grid, 256, 0, stream>>>(x, WF1, dis, bat, nullptr, nullptr, bufA);
  k_agg<<<agg_grid, 256, 0, stream>>>((const u64*)bufA, offs, deg, csr, dis, b1, (u64*)bufB);
  k_stats<<<NG * 16, 256, 0, stream>>>((const uint*)bufB, gstart, statacc);
  k_fin1<<<NG, 128, 0, stream>>>(statacc, counts, gw1, gb1, ga1, Aaff, Baff);

  // layer 2 (norm fused into GEMM A-fragment load, fp8 A-input)
  k_gemm<true><<<gemm_grid, 256, 0, stream>>>(bufB, WF2, dis, bat, Aaff, Baff, bufA);
  k_agg<<<agg_grid, 256, 0, stream>>>((const u64*)bufA, offs, deg, csr, dis, b2, (u64*)bufB);
  k_stats<<<NG * 16, 256, 0, stream>>>((const uint*)bufB, gstart, statacc);
  k_fin2head<<<NG, 128, 0, stream>>>(statacc, counts, gw2, gb2, ga2, Wc, bc, outp);
}

// Round 16
// 200.497 us; speedup vs baseline: 1.2420x; 1.0359x over previous
//
#include <hip/hip_runtime.h>
#include <cstdint>

#define NN 100000
#define NE 1600000
#define NG 64
#define NH 128
#define NC 10
#define EPSV 1e-5f

#define NB 782                       // (NN+127)>>7 coarse buckets (128 nodes each)
#define NBLK 512                     // histogram/scatter blocks
#define EPB ((NE + NBLK - 1) / NBLK) // 3125 edges per block
#define NSCAN (NB * NBLK)            // 400384, divisible by 1024
#define NSB (NSCAN / 1024)           // 391 scan blocks

typedef __attribute__((ext_vector_type(8))) short bf16x8;
typedef __attribute__((ext_vector_type(4))) float f32x4;
typedef __attribute__((ext_vector_type(2))) float f32x2;
typedef unsigned long long u64;
typedef unsigned char uchar;

__device__ __forceinline__ ushort f2b(float f) {
  uint u = __builtin_bit_cast(uint, f);
  u = (u + 0x7FFFu + ((u >> 16) & 1u)) >> 16;
  return (ushort)u;
}
__device__ __forceinline__ float b2f(ushort h) {
  return __builtin_bit_cast(float, ((uint)h) << 16);
}

// ---------------- merged prep: gstart/counts + zero rows (blk 0), W pre-pack (blk 1..16),
//                  coarse histogram (blk 17..528) ----------------
__global__ __launch_bounds__(256) void k_prep0(const int* __restrict__ batch,
                                               int* __restrict__ gstart, int* __restrict__ counts,
                                               u64* __restrict__ zrowA, u64* __restrict__ zrowB,
                                               const float* __restrict__ W1, ushort* __restrict__ WF1,
                                               const float* __restrict__ W2, ushort* __restrict__ WF2,
                                               const int* __restrict__ ei, int* __restrict__ ghist) {
  int b = blockIdx.x;
  if (b == 0) {
    __shared__ int lb[NG + 1];
    int t = threadIdx.x;
    if (t <= NG) {                    // first index with batch[i] >= t (batch is sorted)
      int lo = 0, hi = NN;
      while (lo < hi) { int mid = (lo + hi) >> 1; if (batch[mid] < t) lo = mid + 1; else hi = mid; }
      lb[t] = lo;
    }
    if (t >= 96 && t < 112) zrowA[t - 96] = 0ull;   // 16 u64 = 128 B row NN
    if (t >= 112 && t < 128) zrowB[t - 112] = 0ull;
    __syncthreads();
    if (t < NG) { gstart[t] = lb[t]; counts[t] = lb[t + 1] - lb[t]; }
    if (t == 0) gstart[NG] = NN;
  } else if (b <= 16) {
    int tt = (b - 1) * 256 + threadIdx.x;           // 0..4095
    const float* W = (tt < 2048) ? W1 : W2;
    ushort* WF = (tt < 2048) ? WF1 : WF2;
    int t = tt & 2047;
    int lane = t & 63, nk = t >> 6;
    int n = nk >> 2, ks = nk & 3;
    int col = n * 16 + (lane & 15);
    int k0 = ks * 32 + (lane >> 4) * 8;
#pragma unroll
    for (int j = 0; j < 8; ++j) WF[(size_t)t * 8 + j] = f2b(W[(k0 + j) * NH + col]);
  } else {
    __shared__ int h[NB];
    int t = threadIdx.x, blk = b - 17;              // 0..511
    for (int i = t; i < NB; i += 256) h[i] = 0;
    __syncthreads();
    int e0 = blk * EPB, e1 = min(NE, e0 + EPB);
    for (int e = e0 + t; e < e1; e += 256) atomicAdd(&h[ei[NE + e] >> 7], 1);
    __syncthreads();
    for (int i = t; i < NB; i += 256) ghist[i * NBLK + blk] = h[i];
  }
}

__global__ __launch_bounds__(256) void k_scan1g(int* __restrict__ data, int* __restrict__ bsums) {
  __shared__ int sh[256];
  int t = threadIdx.x;
  int base = blockIdx.x * 1024 + t * 4;
  int4 v = *reinterpret_cast<const int4*>(data + base);
  int s = v.x + v.y + v.z + v.w;
  sh[t] = s;
  __syncthreads();
  for (int o = 1; o < 256; o <<= 1) {
    int x = (t >= o) ? sh[t - o] : 0;
    __syncthreads();
    sh[t] += x;
    __syncthreads();
  }
  int ex = sh[t] - s;
  int4 o4;
  o4.x = ex; o4.y = ex + v.x; o4.z = ex + v.x + v.y; o4.w = ex + v.x + v.y + v.z;
  *reinterpret_cast<int4*>(data + base) = o4;
  if (t == 255) bsums[blockIdx.x] = sh[255];
}

__global__ __launch_bounds__(512) void k_scan2(int* bsums, int nb) {
  __shared__ int sh[512];
  int t = threadIdx.x;
  int v = (t < nb) ? bsums[t] : 0;
  sh[t] = v;
  __syncthreads();
  for (int o = 1; o < 512; o <<= 1) {
    int x = (t >= o) ? sh[t - o] : 0;
    __syncthreads();
    sh[t] += x;
    __syncthreads();
  }
  if (t < nb) bsums[t] = sh[t] - v;   // exclusive
}

// scatter: pack (dlocal, src) into one int: (d&127)<<17 | s  (s < 2^17)
// ghist holds per-1024-chunk exclusive scans; global offset = ghist[idx] + bsums[idx>>10]
__global__ __launch_bounds__(256) void k_scatter(const int* __restrict__ ei, const int* __restrict__ ghist,
                                                 const int* __restrict__ bsums, int* __restrict__ tmp) {
  __shared__ int cur[NB];
  int t = threadIdx.x, blk = blockIdx.x;
  for (int i = t; i < NB; i += 256) {
    int idx = i * NBLK + blk;
    cur[i] = ghist[idx] + bsums[idx >> 10];
  }
  __syncthreads();
  int e0 = blk * EPB, e1 = min(NE, e0 + EPB);
  for (int e = e0 + t; e < e1; e += 256) {
    int d = ei[NE + e], s = ei[e];
    int p = atomicAdd(&cur[d >> 7], 1);   // LDS atomic (fast, block-local)
    tmp[p] = ((d & 127) << 17) | s;
  }
}

// fine bucket: per-node deg/offs/dis + CSR
__global__ __launch_bounds__(256) void k_fine(const int* __restrict__ tmp, const int* __restrict__ ghist,
                                              const int* __restrict__ bsums,
                                              int* __restrict__ deg, int* __restrict__ offs,
                                              float* __restrict__ dis, int* __restrict__ csr) {
  __shared__ int fh[128], fsc[128], fc[128];
  int b = blockIdx.x, t = threadIdx.x;
  int idx0 = b * NBLK;
  int bs = ghist[idx0] + bsums[idx0 >> 10];
  int be = NE;
  if (b + 1 < NB) {
    int idx1 = (b + 1) * NBLK;
    be = ghist[idx1] + bsums[idx1 >> 10];
  }
  if (t < 128) fh[t] = 0;
  __syncthreads();
  for (int e = bs + t; e < be; e += 256) atomicAdd(&fh[tmp[e] >> 17], 1);
  __syncthreads();
  if (t < 128) fsc[t] = fh[t];
  __syncthreads();
  for (int o = 1; o < 128; o <<= 1) {
    int x = 0;
    if (t < 128 && t >= o) x = fsc[t - o];
    __syncthreads();
    if (t < 128) fsc[t] += x;
    __syncthreads();
  }
  if (t < 128) {
    int ex = fsc[t] - fh[t];
    int node = b * 128 + t;
    fc[t] = bs + ex;
    if (node < NN) {
      deg[node] = fh[t];
      offs[node] = bs + ex;
      dis[node] = rsqrtf((float)(fh[t] + 1));   // +1 self-loop
    }
  }
  __syncthreads();
  for (int e = bs + t; e < be; e += 256) {
    int v = tmp[e];
    int p = atomicAdd(&fc[v >> 17], 1);
    csr[p] = v & 0x1FFFF;
  }
}

// ---------------- MFMA GEMM: hs_fp8 = (norm?(X) @ W) * dis ----------------
// Wave = 16 rows x 128 cols. Block = 4 waves = 64 rows. NORM path reads fp8 A-input.
template <bool NORM>
__global__ __launch_bounds__(256) void k_gemm(const void* __restrict__ Xv, const ushort* __restrict__ WF,
                                              const float* __restrict__ dis, const int* __restrict__ batch,
                                              const float* __restrict__ Aaff, const float* __restrict__ Baff,
                                              uchar* __restrict__ out) {
  __shared__ uint sds[4][512];            // per-wave 2KB fp8 staging
  int t = threadIdx.x;
  int w = t >> 6, lane = t & 63;
  int r0 = blockIdx.x * 64 + w * 16;
  int arow = r0 + (lane & 15);
  int khi = lane >> 4;                    // 0..3
  int arowc = (arow < NN) ? arow : (NN - 1);

  f32x4 acc[8];
#pragma unroll
  for (int n = 0; n < 8; ++n) acc[n] = (f32x4){0.f, 0.f, 0.f, 0.f};

  int g = 0;
  if (NORM) g = batch[arowc];
  const bf16x8* WFv = reinterpret_cast<const bf16x8*>(WF);

#pragma unroll
  for (int ks = 0; ks < 4; ++ks) {
    int k0 = ks * 32 + khi * 8;
    bf16x8 a;
    if (!NORM) {
      const float* X = (const float*)Xv;
      float4 x0 = *reinterpret_cast<const float4*>(X + (size_t)arowc * NH + k0);
      float4 x1 = *reinterpret_cast<const float4*>(X + (size_t)arowc * NH + k0 + 4);
      a[0] = (short)f2b(x0.x); a[1] = (short)f2b(x0.y); a[2] = (short)f2b(x0.z); a[3] = (short)f2b(x0.w);
      a[4] = (short)f2b(x1.x); a[5] = (short)f2b(x1.y); a[6] = (short)f2b(x1.z); a[7] = (short)f2b(x1.w);
    } else {
      const uchar* X8 = (const uchar*)Xv;  // fp8 [node][128]
      u64 v = *reinterpret_cast<const u64*>(X8 + (size_t)arowc * NH + k0);
      uint lo = (uint)v, hi = (uint)(v >> 32);
      f32x2 x01 = __builtin_amdgcn_cvt_pk_f32_fp8((int)lo, false);
      f32x2 x23 = __builtin_amdgcn_cvt_pk_f32_fp8((int)lo, true);
      f32x2 x45 = __builtin_amdgcn_cvt_pk_f32_fp8((int)hi, false);
      f32x2 x67 = __builtin_amdgcn_cvt_pk_f32_fp8((int)hi, true);
      float4 A0 = *reinterpret_cast<const float4*>(Aaff + g * NH + k0);
      float4 A1 = *reinterpret_cast<const float4*>(Aaff + g * NH + k0 + 4);
      float4 B0 = *reinterpret_cast<const float4*>(Baff + g * NH + k0);
      float4 B1 = *reinterpret_cast<const float4*>(Baff + g * NH + k0 + 4);
      a[0] = (short)f2b(fmaf(A0.x, x01[0], B0.x));
      a[1] = (short)f2b(fmaf(A0.y, x01[1], B0.y));
      a[2] = (short)f2b(fmaf(A0.z, x23[0], B0.z));
      a[3] = (short)f2b(fmaf(A0.w, x23[1], B0.w));
      a[4] = (short)f2b(fmaf(A1.x, x45[0], B1.x));
      a[5] = (short)f2b(fmaf(A1.y, x45[1], B1.y));
      a[6] = (short)f2b(fmaf(A1.z, x67[0], B1.z));
      a[7] = (short)f2b(fmaf(A1.w, x67[1], B1.w));
    }
#pragma unroll
    for (int n = 0; n < 8; ++n) {
      bf16x8 b = WFv[(n * 4 + ks) * 64 + lane];
      acc[n] = __builtin_amdgcn_mfma_f32_16x16x32_bf16(a, b, acc[n], 0, 0, 0);
    }
  }

  // epilogue: D (col = n*16 + (lane&15), row = khi*4 + reg) -> fp8 bytes in LDS
  int colb = lane & 15;
  uchar* sb = (uchar*)sds[w];
#pragma unroll
  for (int reg = 0; reg < 4; ++reg) {
    int row = khi * 4 + reg;
    int grow = r0 + row;
    float d = (grow < NN) ? dis[grow] : 0.f;
#pragma unroll
    for (int n = 0; n < 8; n += 2) {
      int p2 = __builtin_amdgcn_cvt_pk_fp8_f32(acc[n][reg] * d, acc[n + 1][reg] * d, 0, false);
      sb[row * 128 + n * 16 + colb] = (uchar)(p2 & 0xFF);
      sb[row * 128 + (n + 1) * 16 + colb] = (uchar)((p2 >> 8) & 0xFF);
    }
  }
  __syncthreads();
  // coalesced write-out: 16 rows x 128B contiguous per wave
  const u64* ss = (const u64*)sds[w];
  u64* gout = (u64*)(out + (size_t)r0 * 128);
#pragma unroll
  for (int it = 0; it < 4; ++it) {
    int idx = it * 64 + lane;
    int row = idx >> 4;
    if (r0 + row < NN) __builtin_nontemporal_store(ss[idx], &gout[idx]);
  }
}

// ---------------- aggregation: t = relu(dis[i]*(hs[i]+sum_src hs[src]) + b), fp8 in/out ----------------
// FOUR nodes per wave, group-owns-node: each 16-lane group processes one node entirely
// (lane = 8 feats). 16 edge-gathers per batch all independent -> 4 concurrent chains/wave.
// No cross-lane combine. Invalid slots read zero row NN.
__global__ __launch_bounds__(256) void k_agg(const u64* __restrict__ hf8, const int* __restrict__ offs,
                                             const int* __restrict__ deg, const int* __restrict__ csr,
                                             const float* __restrict__ dis, const float* __restrict__ bias,
                                             u64* __restrict__ outb) {
  int w = threadIdx.x >> 6, lane = threadIdx.x & 63;
  int grp = lane >> 4, sub = lane & 15;
  int node = (blockIdx.x * 4 + w) * 4 + grp;   // 16 nodes per block; NN % 16 == 0
  f32x2 a01 = (f32x2){0.f, 0.f}, a23 = (f32x2){0.f, 0.f};
  f32x2 a45 = (f32x2){0.f, 0.f}, a67 = (f32x2){0.f, 0.f};
#define ACCUM(V)                                                          \
  {                                                                       \
    uint lo_ = (uint)(V), hi_ = (uint)((V) >> 32);                        \
    a01 += __builtin_amdgcn_cvt_pk_f32_fp8((int)lo_, false);              \
    a23 += __builtin_amdgcn_cvt_pk_f32_fp8((int)lo_, true);               \
    a45 += __builtin_amdgcn_cvt_pk_f32_fp8((int)hi_, false);              \
    a67 += __builtin_amdgcn_cvt_pk_f32_fp8((int)hi_, true);               \
  }
  int beg = __builtin_nontemporal_load(offs + node);
  int cnt = __builtin_nontemporal_load(deg + node);
  {                                     // self term
    u64 v = hf8[(size_t)node * 16 + sub];
    ACCUM(v);
  }
  int lim = max(beg + cnt - 1, 0);
  int endp = beg + cnt;
  // batch of 16 edges: all csr loads + gathers independent (full unroll)
#define BATCH(IBASE)                                                      \
  {                                                                       \
    int pb = beg + (IBASE);                                               \
    int c_[16];                                                           \
    _Pragma("unroll")                                                     \
    for (int j = 0; j < 16; ++j)                                          \
      c_[j] = __builtin_nontemporal_load(csr + min(pb + j, lim));         \
    u64 v_[16];                                                           \
    _Pragma("unroll")                                                     \
    for (int j = 0; j < 16; ++j) {                                        \
      int s = (pb + j < endp) ? c_[j] : NN;                               \
      v_[j] = hf8[(size_t)s * 16 + sub];                                  \
    }                                                                     \
    _Pragma("unroll")                                                     \
    for (int j = 0; j < 16; ++j) ACCUM(v_[j]);                            \
  }
  BATCH(0);
  for (int i = 16; i < cnt; i += 16) BATCH(i);   // per-group divergent, rare past 32
#undef BATCH
#undef ACCUM
  float d = dis[node];
  float4 bA = *reinterpret_cast<const float4*>(bias + sub * 8);
  float4 bB = *reinterpret_cast<const float4*>(bias + sub * 8 + 4);
  float o0 = fmaxf(fmaf(d, a01[0], bA.x), 0.f);
  float o1 = fmaxf(fmaf(d, a01[1], bA.y), 0.f);
  float o2 = fmaxf(fmaf(d, a23[0], bA.z), 0.f);
  float o3 = fmaxf(fmaf(d, a23[1], bA.w), 0.f);
  float o4 = fmaxf(fmaf(d, a45[0], bB.x), 0.f);
  float o5 = fmaxf(fmaf(d, a45[1], bB.y), 0.f);
  float o6 = fmaxf(fmaf(d, a67[0], bB.z), 0.f);
  float o7 = fmaxf(fmaf(d, a67[1], bB.w), 0.f);
  uint b01 = (uint)__builtin_amdgcn_cvt_pk_fp8_f32(o0, o1, 0, false) & 0xFFFFu;
  uint b23 = (uint)__builtin_amdgcn_cvt_pk_fp8_f32(o2, o3, 0, false) & 0xFFFFu;
  uint b45 = (uint)__builtin_amdgcn_cvt_pk_fp8_f32(o4, o5, 0, false) & 0xFFFFu;
  uint b67 = (uint)__builtin_amdgcn_cvt_pk_fp8_f32(o6, o7, 0, false) & 0xFFFFu;
  u64 pk = (u64)(b01 | (b23 << 16)) | ((u64)(b45 | (b67 << 16)) << 32);
  __builtin_nontemporal_store(pk, &outb[(size_t)node * 16 + sub]);
}

// ---------------- GraphNorm stats: per-(g,f) sum & sumsq partials, fp8 input ----------------
__global__ __launch_bounds__(256) void k_stats(const uint* __restrict__ t8, const int* __restrict__ gstart,
                                               float* __restrict__ acc) {
  int g = blockIdx.x >> 4, s = blockIdx.x & 15;
  int beg = gstart[g], end = gstart[g + 1];
  int j = threadIdx.x & 31, q = threadIdx.x >> 5;   // 32 uints/row (4 feats each), 8 row-groups
  f32x2 s01 = (f32x2){0.f, 0.f}, s23 = (f32x2){0.f, 0.f};
  f32x2 q01 = (f32x2){0.f, 0.f}, q23 = (f32x2){0.f, 0.f};
  for (int n = beg + s * 8 + q; n < end; n += 128) {
    uint v = t8[(size_t)n * 32 + j];
    f32x2 f01 = __builtin_amdgcn_cvt_pk_f32_fp8((int)v, false);
    f32x2 f23 = __builtin_amdgcn_cvt_pk_f32_fp8((int)v, true);
    s01 += f01; s23 += f23;
    q01 += f01 * f01; q23 += f23 * f23;
  }
  __shared__ float shs[256][4];
  __shared__ float shq[256][4];
  int t = threadIdx.x;
  shs[t][0] = s01[0]; shs[t][1] = s01[1]; shs[t][2] = s23[0]; shs[t][3] = s23[1];
  shq[t][0] = q01[0]; shq[t][1] = q01[1]; shq[t][2] = q23[0]; shq[t][3] = q23[1];
  __syncthreads();
  if (q == 0) {
    float sm[4], sq[4];
#pragma unroll
    for (int k = 0; k < 4; ++k) { sm[k] = shs[j][k]; sq[k] = shq[j][k]; }
#pragma unroll
    for (int qq = 1; qq < 8; ++qq) {
      int idx = qq * 32 + j;
#pragma unroll
      for (int k = 0; k < 4; ++k) { sm[k] += shs[idx][k]; sq[k] += shq[idx][k]; }
    }
    int f = j * 4;
    float* dst = acc + (size_t)(s * NG + g) * 2 * NH;
#pragma unroll
    for (int k = 0; k < 4; ++k) { dst[f + k] = sm[k]; dst[NH + f + k] = sq[k]; }
  }
}

__global__ __launch_bounds__(128) void k_fin1(const float* __restrict__ acc, const int* __restrict__ counts,
                                              const float* __restrict__ gw, const float* __restrict__ gb,
                                              const float* __restrict__ ga,
                                              float* __restrict__ Aaff, float* __restrict__ Baff) {
  int g = blockIdx.x, f = threadIdx.x;
  float sum = 0.f, sq = 0.f;
#pragma unroll 4
  for (int s = 0; s < 16; ++s) {
    const float* d = acc + (size_t)(s * NG + g) * 2 * NH;
    sum += d[f];
    sq += d[NH + f];
  }
  float cnt = fmaxf((float)counts[g], 1.f);
  float m = sum / cnt;
  float ex2 = sq / cnt;
  float a = ga[f];
  float var = ex2 - 2.f * a * m * m + a * a * m * m;
  float rstd = rsqrtf(var + EPSV);
  float A = gw[f] * rstd;
  Aaff[g * NH + f] = A;
  Baff[g * NH + f] = gb[f] - A * a * m;
}

// fused layer-2 finalize + classifier head + softmax
__global__ __launch_bounds__(128) void k_fin2head(const float* __restrict__ acc, const int* __restrict__ counts,
                                                  const float* __restrict__ gw, const float* __restrict__ gb,
                                                  const float* __restrict__ ga, const float* __restrict__ Wc,
                                                  const float* __restrict__ bc, float* __restrict__ outp) {
  __shared__ float pool[NH];
  __shared__ float lg[NC];
  int g = blockIdx.x, f = threadIdx.x;
  float sum = 0.f, sq = 0.f;
#pragma unroll 4
  for (int s = 0; s < 16; ++s) {
    const float* d = acc + (size_t)(s * NG + g) * 2 * NH;
    sum += d[f];
    sq += d[NH + f];
  }
  float cnt = fmaxf((float)counts[g], 1.f);
  float m = sum / cnt;
  float ex2 = sq / cnt;
  float a = ga[f];
  float var = ex2 - 2.f * a * m * m + a * a * m * m;
  float rstd = rsqrtf(var + EPSV);
  pool[f] = gw[f] * rstd * (m - a * m) + gb[f];
  __syncthreads();
  if (f < NC) {
    float s = bc[f];
    for (int h = 0; h < NH; ++h) s = fmaf(pool[h], Wc[h * NC + f], s);
    lg[f] = s;
  }
  __syncthreads();
  if (f == 0) {
    float mx = lg[0];
    for (int c = 1; c < NC; ++c) mx = fmaxf(mx, lg[c]);
    float ex[NC];
    float ssum = 0.f;
    for (int c = 0; c < NC; ++c) { ex[c] = __expf(lg[c] - mx); ssum += ex[c]; }
    float inv = 1.f / ssum;
    for (int c = 0; c < NC; ++c) outp[g * NC + c] = ex[c] * inv;
  }
}

// ---------------- launch ----------------
extern "C" void kernel_launch(void* const* d_in, const int* in_sizes, int n_in,
                              void* d_out, int out_size, void* d_ws, size_t ws_size,
                              hipStream_t stream) {
  const float* x   = (const float*)d_in[0];
  const int*   ei  = (const int*)d_in[1];
  const int*   bat = (const int*)d_in[2];
  const float* W1  = (const float*)d_in[3];
  const float* b1  = (const float*)d_in[4];
  const float* gw1 = (const float*)d_in[5];
  const float* gb1 = (const float*)d_in[6];
  const float* ga1 = (const float*)d_in[7];
  const float* W2  = (const float*)d_in[8];
  const float* b2  = (const float*)d_in[9];
  const float* gw2 = (const float*)d_in[10];
  const float* gb2 = (const float*)d_in[11];
  const float* ga2 = (const float*)d_in[12];
  const float* Wc  = (const float*)d_in[13];
  const float* bc  = (const float*)d_in[14];
  float* outp = (float*)d_out;

  char* ws = (char*)d_ws;
  size_t off = 0;
  auto alloc = [&](size_t b) { size_t p = off; off += (b + 255) & ~(size_t)255; return p; };
  int*    deg     = (int*)(ws + alloc((size_t)NN * 4));
  float*  dis     = (float*)(ws + alloc((size_t)NN * 4));
  int*    counts  = (int*)(ws + alloc(NG * 4));
  int*    gstart  = (int*)(ws + alloc((NG + 1) * 4));
  int*    offs    = (int*)(ws + alloc((size_t)NN * 4));
  int*    bsums   = (int*)(ws + alloc(512 * 4));
  int*    csr     = (int*)(ws + alloc((size_t)NE * 4));
  float*  statacc = (float*)(ws + alloc((size_t)16 * NG * 2 * NH * 4));   // 1 MB partials
  float*  Aaff    = (float*)(ws + alloc((size_t)NG * NH * 4));
  float*  Baff    = (float*)(ws + alloc((size_t)NG * NH * 4));
  ushort* WF1     = (ushort*)(ws + alloc((size_t)2048 * 8 * 2));
  ushort* WF2     = (ushort*)(ws + alloc((size_t)2048 * 8 * 2));
  uchar*  bufA    = (uchar*)(ws + alloc((size_t)(NN + 1) * NH));   // fp8 + zero row NN
  uchar*  bufB    = (uchar*)(ws + alloc((size_t)(NN + 1) * NH));   // fp8 + zero row NN
  // sort temps alias bufB (dead until first k_agg write): 6.4 (packed int) + 1.6 MB < 12.8 MB
  int* tmp   = (int*)bufB;
  int* ghist = (int*)((char*)bufB + (((size_t)NE * 4 + 255) & ~(size_t)255));
  (void)ws_size; (void)in_sizes; (void)n_in; (void)out_size;

  u64* zrowA = (u64*)(bufA + (size_t)NN * NH);
  u64* zrowB = (u64*)(bufB + (size_t)NN * NH);

  // prep (merged): gstart/counts + zero rows + W pre-pack + coarse hist
  k_prep0<<<529, 256, 0, stream>>>(bat, gstart, counts, zrowA, zrowB, W1, WF1, W2, WF2, ei, ghist);
  k_scan1g<<<NSB, 256, 0, stream>>>(ghist, bsums);
  k_scan2<<<1, 512, 0, stream>>>(bsums, NSB);
  k_scatter<<<NBLK, 256, 0, stream>>>(ei, ghist, bsums, tmp);
  k_fine<<<NB, 256, 0, stream>>>(tmp, ghist, bsums, deg, offs, dis, csr);

  int gemm_grid = (NN + 63) / 64;   // 1563
  int agg_grid  = NN / 16;          // 6250 (4 nodes per wave, group-owns-node)

  // layer 1
  k_gemm<false><<<gemm_grid, 256, 0, stream>>>(x, WF1, dis, bat, nullptr, nullptr, bufA);
  k_agg<<<agg_grid, 256, 0, stream>>>((const u64*)bufA, offs, deg, csr, dis, b1, (u64*)bufB);
  k_stats<<<NG * 16, 256, 0, stream>>>((const uint*)bufB, gstart, statacc);
  k_fin1<<<NG, 128, 0, stream>>>(statacc, counts, gw1, gb1, ga1, Aaff, Baff);

  // layer 2 (norm fused into GEMM A-fragment load, fp8 A-input)
  k_gemm<true><<<gemm_grid, 256, 0, stream>>>(bufB, WF2, dis, bat, Aaff, Baff, bufA);
  k_agg<<<agg_grid, 256, 0, stream>>>((const u64*)bufA, offs, deg, csr, dis, b2, (u64*)bufB);
  k_stats<<<NG * 16, 256, 0, stream>>>((const uint*)bufB, gstart, statacc);
  k_fin2head<<<NG, 128, 0, stream>>>(statacc, counts, gw2, gb2, ga2, Wc, bc, outp);
}